// Round 9
// baseline (4331.812 us; speedup 1.0000x reference)
//
#include <hip/hip_runtime.h>
#include <math.h>

// Problem constants
#define B_ 32
#define T_ 512
#define N_ 512
#define D_ 4
#define H_ 2048
#define C_ 128

typedef __attribute__((ext_vector_type(8))) short short8_t;
typedef __attribute__((ext_vector_type(4))) float float4_t;

// ---------------- helpers ----------------
__device__ __forceinline__ unsigned f2bf(float x) {
    unsigned u = __float_as_uint(x);
    return (u + 0x7fffu + ((u >> 16) & 1u)) >> 16;
}
__device__ __forceinline__ float bf2f(unsigned u) {
    return __uint_as_float(u << 16);
}
#define INV2PI 0.15915494309189535f
__device__ __forceinline__ float sin_hw(float x) {
    float r = x * INV2PI;
    r -= floorf(r);
    return __builtin_amdgcn_sinf(r);
}
__device__ __forceinline__ float cos_hw(float x) {
    float r = x * INV2PI;
    r -= floorf(r);
    return __builtin_amdgcn_cosf(r);
}

// ---------------- f32 -> bf16 straight convert (packed pairs) ----------------
__global__ __launch_bounds__(256) void cvt_bf16_kernel(
    const float* __restrict__ in, unsigned* __restrict__ out, int n2) {
    int i = blockIdx.x * 256 + threadIdx.x;
    if (i < n2) out[i] = f2bf(in[2 * i]) | (f2bf(in[2 * i + 1]) << 16);
}

// ---------------- f32 [R,C] -> bf16 [C,R] transpose-convert ----------------
__global__ __launch_bounds__(256) void cvt_T_kernel(
    const float* __restrict__ in, unsigned short* __restrict__ out, int R, int C) {
    __shared__ float tl[32][33];
    const int tr = blockIdx.y * 32, tc = blockIdx.x * 32;
    const int a = threadIdx.x >> 3, b4 = (threadIdx.x & 7) * 4;
    float4 v = *(const float4*)(in + (size_t)(tr + a) * C + tc + b4);
    tl[a][b4] = v.x; tl[a][b4 + 1] = v.y; tl[a][b4 + 2] = v.z; tl[a][b4 + 3] = v.w;
    __syncthreads();
    unsigned* o32 = (unsigned*)out;
    size_t base = ((size_t)(tc + a) * R + tr + b4) >> 1;
    o32[base]     = f2bf(tl[b4][a])     | (f2bf(tl[b4 + 1][a]) << 16);
    o32[base + 1] = f2bf(tl[b4 + 2][a]) | (f2bf(tl[b4 + 3][a]) << 16);
}

// ---------------- bf16 MFMA GEMM: C[M,N] = A[M,K] @ BT[N,K]^T + bias ----------------
// 128x128 tile, BK=64, 256 threads (4 waves, 2x2), 4x4 frags of 16x16x32.
// EPI: 0 = f32 out, 1 = bf16 out, 2 = mask (sigmoid, scale featb rows in place).
// AREMAP: A row (b,t) read from (b, max(0,t-2)).
template <int EPI, bool AREMAP>
__global__ __launch_bounds__(256) void gemm_bf16(
    const unsigned short* __restrict__ A, const unsigned short* __restrict__ BT,
    const float* __restrict__ bias, void* __restrict__ Cout,
    int M, int N, int K) {
    __shared__ unsigned short Al[128 * 72];
    __shared__ unsigned short Bl[128 * 72];
    const int tid = threadIdx.x;
    const int wid = tid >> 6, l = tid & 63;
    const int c = l & 15, q = l >> 4;
    const int wr = wid >> 1, wc = wid & 1;
    const int m0 = blockIdx.y * 128, n0 = blockIdx.x * 128;
    float4_t acc[4][4];
#pragma unroll
    for (int i = 0; i < 4; ++i)
#pragma unroll
        for (int j = 0; j < 4; ++j) acc[i][j] = (float4_t){0.f, 0.f, 0.f, 0.f};

    const int sr = tid >> 1, sh = tid & 1;
    size_t a_row = (size_t)(m0 + sr);
    if (AREMAP) {
        int tt = (m0 + sr) & 511;
        a_row = (size_t)(((m0 + sr) & ~511) | (tt < 2 ? 0 : tt - 2));
    }
    const unsigned short* ag = A + a_row * K + sh * 32;
    const unsigned short* bg = BT + (size_t)(n0 + sr) * K + sh * 32;
    unsigned short* aw = Al + sr * 72 + sh * 32;
    unsigned short* bw = Bl + sr * 72 + sh * 32;

    for (int k0 = 0; k0 < K; k0 += 64) {
        uint4 av0 = *(const uint4*)(ag);
        uint4 av1 = *(const uint4*)(ag + 8);
        uint4 av2 = *(const uint4*)(ag + 16);
        uint4 av3 = *(const uint4*)(ag + 24);
        uint4 bv0 = *(const uint4*)(bg);
        uint4 bv1 = *(const uint4*)(bg + 8);
        uint4 bv2 = *(const uint4*)(bg + 16);
        uint4 bv3 = *(const uint4*)(bg + 24);
        __syncthreads();  // prior frag reads complete
        *(uint4*)(aw) = av0; *(uint4*)(aw + 8) = av1;
        *(uint4*)(aw + 16) = av2; *(uint4*)(aw + 24) = av3;
        *(uint4*)(bw) = bv0; *(uint4*)(bw + 8) = bv1;
        *(uint4*)(bw + 16) = bv2; *(uint4*)(bw + 24) = bv3;
        __syncthreads();
#pragma unroll
        for (int kk = 0; kk < 2; ++kk) {
            short8_t af[4], bf[4];
#pragma unroll
            for (int mt = 0; mt < 4; ++mt)
                af[mt] = *(const short8_t*)(Al + (wr * 64 + mt * 16 + c) * 72 + kk * 32 + q * 8);
#pragma unroll
            for (int nt = 0; nt < 4; ++nt)
                bf[nt] = *(const short8_t*)(Bl + (wc * 64 + nt * 16 + c) * 72 + kk * 32 + q * 8);
#pragma unroll
            for (int mt = 0; mt < 4; ++mt)
#pragma unroll
                for (int nt = 0; nt < 4; ++nt)
                    acc[mt][nt] = __builtin_amdgcn_mfma_f32_16x16x32_bf16(
                        af[mt], bf[nt], acc[mt][nt], 0, 0, 0);
        }
        ag += 64; bg += 64;
    }

#pragma unroll
    for (int mt = 0; mt < 4; ++mt) {
        int row = m0 + wr * 64 + mt * 16 + q * 4;
#pragma unroll
        for (int nt = 0; nt < 4; ++nt) {
            int col = n0 + wc * 64 + nt * 16 + c;
            float bs = bias[col];
            if (EPI == 0) {
                float* Cf = (float*)Cout;
#pragma unroll
                for (int r = 0; r < 4; ++r)
                    Cf[(size_t)(row + r) * N + col] = acc[mt][nt][r] + bs;
            } else if (EPI == 1) {
                unsigned short* Cb = (unsigned short*)Cout;
#pragma unroll
                for (int r = 0; r < 4; ++r)
                    Cb[(size_t)(row + r) * N + col] = (unsigned short)f2bf(acc[mt][nt][r] + bs);
            } else {
                unsigned short* Fb = (unsigned short*)Cout;
#pragma unroll
                for (int r = 0; r < 4; ++r) {
                    float s = 1.f / (1.f + __expf(-(acc[mt][nt][r] + bs)));
                    unsigned short* fp = Fb + (size_t)(row + r) * 2048 + col * 4;
                    unsigned u0 = *(const unsigned*)fp;
                    unsigned u1 = *(const unsigned*)(fp + 2);
                    float f0 = bf2f(u0 & 0xffffu) * s;
                    float f1 = __uint_as_float(u0 & 0xffff0000u) * s;
                    float f2 = bf2f(u1 & 0xffffu) * s;
                    float f3 = __uint_as_float(u1 & 0xffff0000u) * s;
                    *(unsigned*)fp = f2bf(f0) | (f2bf(f1) << 16);
                    *(unsigned*)(fp + 2) = f2bf(f2) | (f2bf(f3) << 16);
                }
            }
        }
    }
}

// ---------------- LayerNorm + LeakyReLU over bf16 rows of H=2048, in place ----------------
__device__ __forceinline__ float block_sum256(float v, float* red) {
#pragma unroll
    for (int o = 32; o > 0; o >>= 1) v += __shfl_down(v, o, 64);
    int w = threadIdx.x >> 6;
    if ((threadIdx.x & 63) == 0) red[w] = v;
    __syncthreads();
    float r = red[0] + red[1] + red[2] + red[3];
    __syncthreads();
    return r;
}

__global__ __launch_bounds__(256) void ln_leaky_kernel(
    unsigned short* __restrict__ Z, const float* __restrict__ gam,
    const float* __restrict__ bet) {
    __shared__ float red[4];
    unsigned short* zr = Z + (size_t)blockIdx.x * H_;
    const int tid = threadIdx.x;
    float v[8];
    float s = 0.f;
#pragma unroll
    for (int i = 0; i < 8; ++i) { v[i] = bf2f((unsigned)zr[tid + i * 256]); s += v[i]; }
    s = block_sum256(s, red);
    float mu = s * (1.f / H_);
    float qq = 0.f;
#pragma unroll
    for (int i = 0; i < 8; ++i) { float dd = v[i] - mu; qq += dd * dd; }
    qq = block_sum256(qq, red);
    float rs = rsqrtf(qq * (1.f / H_) + 1e-5f);
#pragma unroll
    for (int i = 0; i < 8; ++i) {
        int cc = tid + i * 256;
        float y = (v[i] - mu) * rs * gam[cc] + bet[cc];
        zr[cc] = (unsigned short)f2bf(y > 0.f ? y : 0.1f * y);
    }
}

// ---------------- theta-scan v6: r8 skeleton + PINNED reg tile + batched stream ----------------
// 16 blocks x 1024 threads; block owns 2 batches. Two __syncthreads/step (r8-proven).
// sc split: 16 reg tiles rows 0-255 (PINNED via opaque asm, cannot be rematerialized)
//           + 8 LDS tiles rows 256-383 + 8 L2-stream rows 384-511 (chunked 4x4 prefetch).
// amdgpu_waves_per_eu(4,4): 128-VGPR budget (16-wave block forces 4 waves/SIMD anyway).
#define SCAN_LDS_BYTES 149760
// LDS: lds_sc [128][520]u16 @0 (133120 B) ; XT [16][520]u16 @133120 (16640 B)

__global__ __launch_bounds__(1024) __attribute__((amdgpu_waves_per_eu(4, 4)))
void scan_kernel(
    const unsigned short* __restrict__ scb,  // [512][512] bf16
    const float* __restrict__ gamma,         // [32][512][512] f32
    const float* __restrict__ omega,         // [512][4]
    unsigned short* __restrict__ featb,      // [32][512][2048] bf16: sin dump (pre-g)
    float* __restrict__ msum) {              // [32][512][512] f32: sum_d theta
    extern __shared__ char smem[];
    unsigned short* lds_sc = (unsigned short*)smem;
    unsigned short* XT = (unsigned short*)(smem + 133120);

    const int tid = threadIdx.x;
    const int w = tid >> 6, l = tid & 63;
    const int c = l & 15, q = l >> 4;
    const int h = c >> 3, bd = c & 7, bl = (c >> 2) & 1, d = c & 3;
    const int bglob = (int)blockIdx.x * 2 + bl;
    const int o0 = q * 4 + 2 * h;  // even row offset in tile; lane owns o0, o0+1

    // ---- stage LDS sc tiles (global rows 256..383) ----
    {
        const unsigned* g32 = (const unsigned*)scb;
        unsigned* l32 = (unsigned*)lds_sc;
        for (int it = 0; it < 32; ++it) {
            int idx = it * 1024 + tid;
            int row = idx >> 8, col = idx & 255;
            l32[row * 260 + col] = g32[(256 + row) * 256 + col];
        }
    }
    // ---- register tile (rows [w*16,+16)), PINNED so it cannot be rematerialized ----
    uint4 areg4[16];
    {
        const unsigned short* arow = scb + (size_t)(w * 16 + c) * 512 + q * 8;
#pragma unroll
        for (int kk = 0; kk < 16; ++kk)
            areg4[kk] = *(const uint4*)(arow + kk * 32);
#pragma unroll
        for (int kk = 0; kk < 16; ++kk)
            asm volatile("" : "+v"(areg4[kk].x), "+v"(areg4[kk].y),
                              "+v"(areg4[kk].z), "+v"(areg4[kk].w));
    }
    // second tile source: LDS for waves 0-7 (rows 256..383), L2 stream for waves 8-15
    const unsigned short* al_base = lds_sc + (w * 16 + c) * 520 + q * 8;             // w<8
    const unsigned short* gs_base = scb + (size_t)(256 + w * 16 + c) * 512 + q * 8;  // w>=8
    const int i0 = w * 16 + o0;        // mi=0 global rows (+rr)
    const int i1 = 256 + w * 16 + o0;  // mi=1
    const int i_own = ((l & 2) ? i1 : i0) + (l & 1);  // row this lane dumps after transpose

    float om[2][2], th[2][2], sn[2][2], cs[2][2];
#pragma unroll
    for (int mi = 0; mi < 2; ++mi)
#pragma unroll
        for (int rr = 0; rr < 2; ++rr) {
            int i = (mi ? i1 : i0) + rr;
            om[mi][rr] = omega[i * 4 + d];
            th[mi][rr] = 0.f; sn[mi][rr] = 0.f; cs[mi][rr] = 1.f;
        }
    __syncthreads();

    for (int t = 0; t < T_; ++t) {
        // gamma loads
        float gv[2][2];
        {
            const float* grow = gamma + ((size_t)bglob * 512 + t) * 512;
            gv[0][0] = grow[i0]; gv[0][1] = grow[i0 + 1];
            gv[1][0] = grow[i1]; gv[1][1] = grow[i1 + 1];
        }

        float4_t acc0 = {0.f, 0.f, 0.f, 0.f}, acc1 = {0.f, 0.f, 0.f, 0.f};
        if (t > 0) {
            const unsigned short* bt_base = XT + c * 520 + q * 8;
            if (w < 8) {
#pragma unroll
                for (int kk = 0; kk < 16; ++kk) {
                    short8_t bf = *(const short8_t*)(bt_base + kk * 32);
                    short8_t aL = *(const short8_t*)(al_base + kk * 32);
                    acc0 = __builtin_amdgcn_mfma_f32_16x16x32_bf16(
                        __builtin_bit_cast(short8_t, areg4[kk]), bf, acc0, 0, 0, 0);
                    acc1 = __builtin_amdgcn_mfma_f32_16x16x32_bf16(aL, bf, acc1, 0, 0, 0);
                }
            } else {
#pragma unroll
                for (int ch = 0; ch < 4; ++ch) {
                    // batch-issue 4 L2 loads, then consume in 8 MFMAs
                    uint4 s0 = *(const uint4*)(gs_base + (ch * 4 + 0) * 32);
                    uint4 s1 = *(const uint4*)(gs_base + (ch * 4 + 1) * 32);
                    uint4 s2 = *(const uint4*)(gs_base + (ch * 4 + 2) * 32);
                    uint4 s3 = *(const uint4*)(gs_base + (ch * 4 + 3) * 32);
                    short8_t b0 = *(const short8_t*)(bt_base + (ch * 4 + 0) * 32);
                    short8_t b1 = *(const short8_t*)(bt_base + (ch * 4 + 1) * 32);
                    short8_t b2 = *(const short8_t*)(bt_base + (ch * 4 + 2) * 32);
                    short8_t b3 = *(const short8_t*)(bt_base + (ch * 4 + 3) * 32);
                    acc0 = __builtin_amdgcn_mfma_f32_16x16x32_bf16(
                        __builtin_bit_cast(short8_t, areg4[ch * 4 + 0]), b0, acc0, 0, 0, 0);
                    acc1 = __builtin_amdgcn_mfma_f32_16x16x32_bf16(
                        __builtin_bit_cast(short8_t, s0), b0, acc1, 0, 0, 0);
                    acc0 = __builtin_amdgcn_mfma_f32_16x16x32_bf16(
                        __builtin_bit_cast(short8_t, areg4[ch * 4 + 1]), b1, acc0, 0, 0, 0);
                    acc1 = __builtin_amdgcn_mfma_f32_16x16x32_bf16(
                        __builtin_bit_cast(short8_t, s1), b1, acc1, 0, 0, 0);
                    acc0 = __builtin_amdgcn_mfma_f32_16x16x32_bf16(
                        __builtin_bit_cast(short8_t, areg4[ch * 4 + 2]), b2, acc0, 0, 0, 0);
                    acc1 = __builtin_amdgcn_mfma_f32_16x16x32_bf16(
                        __builtin_bit_cast(short8_t, s2), b2, acc1, 0, 0, 0);
                    acc0 = __builtin_amdgcn_mfma_f32_16x16x32_bf16(
                        __builtin_bit_cast(short8_t, areg4[ch * 4 + 3]), b3, acc0, 0, 0, 0);
                    acc1 = __builtin_amdgcn_mfma_f32_16x16x32_bf16(
                        __builtin_bit_cast(short8_t, s3), b3, acc1, 0, 0, 0);
                }
            }
        }
        __syncthreads();  // sync1: all XT reads of step t complete

        // combine halves, theta update, hw sincos
#pragma unroll
        for (int mi = 0; mi < 2; ++mi) {
            float4_t acc = mi ? acc1 : acc0;
#pragma unroll
            for (int rr = 0; rr < 2; ++rr) {
                float own = h ? acc[2 + rr] : acc[rr];
                float send = h ? acc[rr] : acc[2 + rr];
                float recv = __shfl_xor(send, 8, 64);
                float Sst = h ? recv : own;
                float Sct = h ? own : recv;
                float coup = cs[mi][rr] * Sst - sn[mi][rr] * Sct;
                th[mi][rr] += 0.1f * (om[mi][rr] + gv[mi][rr] + (1.f / 512.f) * coup);
                sn[mi][rr] = sin_hw(th[mi][rr]);
                cs[mi][rr] = cos_hw(th[mi][rr]);
            }
        }

        // msum = sum over d (4-lane group reduce); lane stores its own (mi,rr)'s sum
        float ms00 = th[0][0], ms01 = th[0][1], ms10 = th[1][0], ms11 = th[1][1];
        ms00 += __shfl_xor(ms00, 1, 64); ms00 += __shfl_xor(ms00, 2, 64);
        ms01 += __shfl_xor(ms01, 1, 64); ms01 += __shfl_xor(ms01, 2, 64);
        ms10 += __shfl_xor(ms10, 1, 64); ms10 += __shfl_xor(ms10, 2, 64);
        ms11 += __shfl_xor(ms11, 1, 64); ms11 += __shfl_xor(ms11, 2, 64);
        float msj = (l & 2) ? ((l & 1) ? ms11 : ms10) : ((l & 1) ? ms01 : ms00);
        msum[((size_t)bglob * 512 + t) * 512 + i_own] = msj;

        // write new st/ct into XT (bf16 pairs) for step t+1
        unsigned sp0 = f2bf(sn[0][0]) | (f2bf(sn[0][1]) << 16);
        unsigned cp0 = f2bf(cs[0][0]) | (f2bf(cs[0][1]) << 16);
        unsigned sp1 = f2bf(sn[1][0]) | (f2bf(sn[1][1]) << 16);
        unsigned cp1 = f2bf(cs[1][0]) | (f2bf(cs[1][1]) << 16);
        ((unsigned*)XT)[(bd * 520 + i0) >> 1] = sp0;
        ((unsigned*)XT)[((8 + bd) * 520 + i0) >> 1] = cp0;
        ((unsigned*)XT)[(bd * 520 + i1) >> 1] = sp1;
        ((unsigned*)XT)[((8 + bd) * 520 + i1) >> 1] = cp1;

        // 4x4 lane transpose of sins -> natural feat layout, coalesced 8B store
        {
            float A0 = sn[0][0], A1 = sn[0][1], A2 = sn[1][0], A3 = sn[1][1];
            bool bit0 = (l & 1), bit1 = (l & 2);
            float sA = __shfl_xor(bit0 ? A0 : A1, 1, 64);
            float sB = __shfl_xor(bit0 ? A2 : A3, 1, 64);
            float B0 = bit0 ? sA : A0;
            float B1 = bit0 ? A1 : sA;
            float B2 = bit0 ? sB : A2;
            float B3 = bit0 ? A3 : sB;
            float sC = __shfl_xor(bit1 ? B0 : B2, 2, 64);
            float sD = __shfl_xor(bit1 ? B1 : B3, 2, 64);
            float c0 = bit1 ? sC : B0;
            float c1 = bit1 ? sD : B1;
            float c2 = bit1 ? B2 : sC;
            float c3 = bit1 ? B3 : sD;
            uint2 pk;
            pk.x = f2bf(c0) | (f2bf(c1) << 16);
            pk.y = f2bf(c2) | (f2bf(c3) << 16);
            *(uint2*)(featb + ((size_t)bglob * 512 + t) * 2048 + i_own * 4) = pk;
        }
        __syncthreads();  // sync2: XT writes visible for step t+1
    }
}

// ---------------- post: g from msum, featb *= g (in place), gb = bf16(g_t) ----------------
__global__ __launch_bounds__(256) void post_kernel(
    const float* __restrict__ msum,      // [32][512][512]
    unsigned short* __restrict__ featb,  // [32][512][2048] RMW
    unsigned short* __restrict__ gb) {   // [32][512][512]
    int idx = blockIdx.x * 256 + threadIdx.x;  // 8,388,608
    int i = idx & 511;
    int t = (idx >> 9) & 511;
    int b = idx >> 18;
    int t2 = t < 2 ? 0 : t - 2;
    float m2 = msum[((size_t)b * 512 + t2) * 512 + i];
    float g = 0.5f + 0.5f * sin_hw(m2 * 0.25f);
    uint2* fp = (uint2*)(featb + ((size_t)b * 512 + t) * 2048 + i * 4);
    uint2 v = *fp;
    float f0 = bf2f(v.x & 0xffffu) * g;
    float f1 = __uint_as_float(v.x & 0xffff0000u) * g;
    float f2 = bf2f(v.y & 0xffffu) * g;
    float f3 = __uint_as_float(v.y & 0xffff0000u) * g;
    v.x = f2bf(f0) | (f2bf(f1) << 16);
    v.y = f2bf(f2) | (f2bf(f3) << 16);
    *fp = v;
    float mt = msum[((size_t)b * 512 + t) * 512 + i];
    gb[((size_t)b * 512 + t) * 512 + i] =
        (unsigned short)f2bf(0.5f + 0.5f * sin_hw(mt * 0.25f));
}

// ---------------- LIF membrane scan: cur(f32) -> spike f32 (in place) + bf16 copy ----------------
__global__ __launch_bounds__(256) void mem_scan_kernel(
    float* __restrict__ io, unsigned short* __restrict__ spb) {
    int tid = blockIdx.x * 256 + threadIdx.x;  // 65536 = B*H
    int h = tid & (H_ - 1), b = tid >> 11;
    float mem = 0.f;
    float* base = io + (size_t)b * T_ * H_ + h;
    unsigned short* sb = spb + (size_t)b * T_ * H_ + h;
    for (int t = 0; t < T_; ++t) {
        float cur = base[(size_t)t * H_];
        mem = 0.5f * mem + cur;
        float sp = 1.f / (1.f + __expf(-4.f * (mem - 1.f)));
        mem -= sp;
        base[(size_t)t * H_] = sp;
        sb[(size_t)t * H_] = (unsigned short)f2bf(sp);
    }
}

// ---------------- conv1d(k=5,pad=2) over T + log_softmax over C ----------------
__global__ __launch_bounds__(128) void conv_lsm_kernel(
    const float* __restrict__ snn, const float* __restrict__ Wc,
    const float* __restrict__ bc, float* __restrict__ out0) {
    __shared__ float sl[36 * 128];
    const int b = blockIdx.x >> 4;
    const int tt0 = (blockIdx.x & 15) * 32;
    const int co = threadIdx.x;
    for (int r = 0; r < 36; ++r) {
        int t = tt0 + r - 2;
        sl[r * 128 + co] = (t >= 0 && t < T_) ? snn[(size_t)(b * T_ + t) * 128 + co] : 0.f;
    }
    __syncthreads();
    float acc[32];
#pragma unroll
    for (int i = 0; i < 32; ++i) acc[i] = 0.f;
    for (int ci = 0; ci < 128; ++ci) {
        const float* wp = &Wc[(size_t)(co * 128 + ci) * 5];
        float w0 = wp[0], w1 = wp[1], w2 = wp[2], w3 = wp[3], w4 = wp[4];
        const float* col = &sl[ci];
        float r0 = col[0 * 128], r1 = col[1 * 128], r2 = col[2 * 128], r3 = col[3 * 128];
#pragma unroll
        for (int i = 0; i < 32; ++i) {
            float r4 = col[(i + 4) * 128];
            acc[i] += w0 * r0 + w1 * r1 + w2 * r2 + w3 * r3 + w4 * r4;
            r0 = r1; r1 = r2; r2 = r3; r3 = r4;
        }
    }
    float bco = bc[co];
    __syncthreads();
    float* cl = sl;
#pragma unroll
    for (int i = 0; i < 32; ++i) cl[i * 129 + co] = acc[i] + bco;
    __syncthreads();
    if (co < 32) {
        int t = tt0 + co;
        float mx = -3.4e38f;
        for (int cc = 0; cc < 128; ++cc) mx = fmaxf(mx, cl[co * 129 + cc]);
        float se = 0.f;
        for (int cc = 0; cc < 128; ++cc) se += __expf(cl[co * 129 + cc] - mx);
        float lse = mx + __logf(se);
        for (int cc = 0; cc < 128; ++cc)
            out0[((size_t)(b * 128 + cc)) * T_ + t] = cl[co * 129 + cc] - lse;
    }
}

// ---------------- launch ----------------
extern "C" void kernel_launch(void* const* d_in, const int* in_sizes, int n_in,
                              void* d_out, int out_size, void* d_ws, size_t ws_size,
                              hipStream_t stream) {
    (void)in_sizes; (void)n_in; (void)out_size; (void)ws_size;
    const float* x      = (const float*)d_in[0];
    const float* sc     = (const float*)d_in[1];
    const float* W_proj = (const float*)d_in[2];
    const float* b_proj = (const float*)d_in[3];
    const float* ln_g   = (const float*)d_in[4];
    const float* ln_b   = (const float*)d_in[5];
    const float* W_enc  = (const float*)d_in[6];
    const float* b_enc  = (const float*)d_in[7];
    const float* omega  = (const float*)d_in[8];
    const float* W_mask = (const float*)d_in[9];
    const float* b_mask = (const float*)d_in[10];
    const float* W_in   = (const float*)d_in[11];
    const float* b_in   = (const float*)d_in[12];
    const float* W_out  = (const float*)d_in[13];
    const float* b_out  = (const float*)d_in[14];
    const float* W_conv = (const float*)d_in[15];
    const float* b_conv = (const float*)d_in[16];

    float* out0 = (float*)d_out;                   // [B,C,T]
    float* out1 = out0 + (size_t)B_ * C_ * T_;     // [B,T,H] f32: cur -> spikes

    const int M = B_ * T_;  // 16384
    char* w = (char*)d_ws;
    float*          gamma  = (float*)w;                         // @0          33,554,432
    unsigned short* featb  = (unsigned short*)(w + 33554432);   // @33.5M      67,108,864
    float*          msum   = (float*)(w + 100663296);           // @100.7M     33,554,432
    unsigned short* gb     = (unsigned short*)(w + 134217728);  // @134.2M     16,777,216
    unsigned short* scb    = (unsigned short*)(w + 150994944);  // @151.0M        524,288
    unsigned short* wprojT = (unsigned short*)(w + 151519232);  // [2048,512]   2,097,152
    unsigned short* wencT  = (unsigned short*)(w + 153616384);  // [512,2048]   2,097,152
    unsigned short* winT   = (unsigned short*)(w + 155713536);  // [2048,2048]  8,388,608
    unsigned short* woutT  = (unsigned short*)(w + 164102144);  // [128,2048]     524,288
    unsigned short* wmT    = (unsigned short*)(w + 164626432);  // [512,512]      524,288
    unsigned short* xb  = gb;      // alias: xb dead before post writes gb
    unsigned short* Zb  = featb;   // alias: Z dead before scan writes featb
    unsigned short* spb = featb;   // alias: featb dead after G3
    float* snn_pre = gamma;        // alias: gamma dead after scan

    // conversions
    cvt_bf16_kernel<<<512, 256, 0, stream>>>(sc, (unsigned*)scb, 131072);
    cvt_bf16_kernel<<<16384, 256, 0, stream>>>(x, (unsigned*)xb, 4194304);
    cvt_T_kernel<<<dim3(64, 16), 256, 0, stream>>>(W_proj, wprojT, 512, 2048);
    cvt_T_kernel<<<dim3(16, 64), 256, 0, stream>>>(W_enc, wencT, 2048, 512);
    cvt_T_kernel<<<dim3(64, 64), 256, 0, stream>>>(W_in, winT, 2048, 2048);
    cvt_T_kernel<<<dim3(4, 64), 256, 0, stream>>>(W_out, woutT, 2048, 128);
    cvt_T_kernel<<<dim3(16, 16), 256, 0, stream>>>(W_mask, wmT, 512, 512);

    // G1: Zb = bf16(x @ W_proj + b_proj)
    gemm_bf16<1, false><<<dim3(16, 128), 256, 0, stream>>>(xb, wprojT, b_proj, Zb, M, H_, N_);
    // LN + LeakyReLU in place (bf16)
    ln_leaky_kernel<<<M, 256, 0, stream>>>(Zb, ln_g, ln_b);
    // G2: gamma(f32) = Zb @ W_enc + b_enc
    gemm_bf16<0, false><<<dim3(4, 128), 256, 0, stream>>>(Zb, wencT, b_enc, gamma, M, N_, H_);
    // theta scan -> featb (sin dump), msum
    scan_kernel<<<16, 1024, SCAN_LDS_BYTES, stream>>>(scb, gamma, omega, featb, msum);
    // post: featb *= g_{t-2}, gb = bf16(g(theta_t))
    post_kernel<<<32768, 256, 0, stream>>>(msum, featb, gb);
    // deferred mask: featb *= sigmoid(gb_shift @ W_mask + b_mask)
    gemm_bf16<2, true><<<dim3(4, 128), 256, 0, stream>>>(gb, wmT, b_mask, featb, M, N_, N_);
    // G3: cur(f32, out1) = featb @ W_in + b_in
    gemm_bf16<0, false><<<dim3(16, 128), 256, 0, stream>>>(featb, winT, b_in, out1, M, H_, N_ * D_);
    // LIF membrane scan in place + bf16 spikes
    mem_scan_kernel<<<256, 256, 0, stream>>>(out1, spb);
    // G4: snn_pre(f32) = spikes @ W_out + b_out
    gemm_bf16<0, false><<<dim3(1, 128), 256, 0, stream>>>(spb, woutT, b_out, snn_pre, M, C_, H_);
    // conv1d + log_softmax -> out0
    conv_lsm_kernel<<<dim3(B_ * 16), 128, 0, stream>>>(snn_pre, W_conv, b_conv, out0);
}

// Round 10
// 3415.336 us; speedup vs baseline: 1.2683x; 1.2683x over previous
//
#include <hip/hip_runtime.h>
#include <math.h>

// Problem constants
#define B_ 32
#define T_ 512
#define N_ 512
#define D_ 4
#define H_ 2048
#define C_ 128

typedef __attribute__((ext_vector_type(8))) short short8_t;
typedef __attribute__((ext_vector_type(4))) float float4_t;

// ---------------- helpers ----------------
__device__ __forceinline__ unsigned f2bf(float x) {
    unsigned u = __float_as_uint(x);
    return (u + 0x7fffu + ((u >> 16) & 1u)) >> 16;
}
__device__ __forceinline__ float bf2f(unsigned u) {
    return __uint_as_float(u << 16);
}
#define INV2PI 0.15915494309189535f
__device__ __forceinline__ float sin_hw(float x) {
    float r = x * INV2PI;
    r -= floorf(r);
    return __builtin_amdgcn_sinf(r);
}
__device__ __forceinline__ float cos_hw(float x) {
    float r = x * INV2PI;
    r -= floorf(r);
    return __builtin_amdgcn_cosf(r);
}

// ---------------- f32 -> bf16 straight convert (packed pairs) ----------------
__global__ __launch_bounds__(256) void cvt_bf16_kernel(
    const float* __restrict__ in, unsigned* __restrict__ out, int n2) {
    int i = blockIdx.x * 256 + threadIdx.x;
    if (i < n2) out[i] = f2bf(in[2 * i]) | (f2bf(in[2 * i + 1]) << 16);
}

// ---------------- f32 [R,C] -> bf16 [C,R] transpose-convert ----------------
__global__ __launch_bounds__(256) void cvt_T_kernel(
    const float* __restrict__ in, unsigned short* __restrict__ out, int R, int C) {
    __shared__ float tl[32][33];
    const int tr = blockIdx.y * 32, tc = blockIdx.x * 32;
    const int a = threadIdx.x >> 3, b4 = (threadIdx.x & 7) * 4;
    float4 v = *(const float4*)(in + (size_t)(tr + a) * C + tc + b4);
    tl[a][b4] = v.x; tl[a][b4 + 1] = v.y; tl[a][b4 + 2] = v.z; tl[a][b4 + 3] = v.w;
    __syncthreads();
    unsigned* o32 = (unsigned*)out;
    size_t base = ((size_t)(tc + a) * R + tr + b4) >> 1;
    o32[base]     = f2bf(tl[b4][a])     | (f2bf(tl[b4 + 1][a]) << 16);
    o32[base + 1] = f2bf(tl[b4 + 2][a]) | (f2bf(tl[b4 + 3][a]) << 16);
}

// ---------------- bf16 MFMA GEMM: C[M,N] = A[M,K] @ BT[N,K]^T + bias ----------------
// 128x128 tile, BK=64, 256 threads (4 waves, 2x2), 4x4 frags of 16x16x32.
// EPI: 0 = f32 out, 1 = bf16 out, 2 = mask (sigmoid, scale featb rows in place).
// AREMAP: A row (b,t) read from (b, max(0,t-2)).
template <int EPI, bool AREMAP>
__global__ __launch_bounds__(256) void gemm_bf16(
    const unsigned short* __restrict__ A, const unsigned short* __restrict__ BT,
    const float* __restrict__ bias, void* __restrict__ Cout,
    int M, int N, int K) {
    __shared__ unsigned short Al[128 * 72];
    __shared__ unsigned short Bl[128 * 72];
    const int tid = threadIdx.x;
    const int wid = tid >> 6, l = tid & 63;
    const int c = l & 15, q = l >> 4;
    const int wr = wid >> 1, wc = wid & 1;
    const int m0 = blockIdx.y * 128, n0 = blockIdx.x * 128;
    float4_t acc[4][4];
#pragma unroll
    for (int i = 0; i < 4; ++i)
#pragma unroll
        for (int j = 0; j < 4; ++j) acc[i][j] = (float4_t){0.f, 0.f, 0.f, 0.f};

    const int sr = tid >> 1, sh = tid & 1;
    size_t a_row = (size_t)(m0 + sr);
    if (AREMAP) {
        int tt = (m0 + sr) & 511;
        a_row = (size_t)(((m0 + sr) & ~511) | (tt < 2 ? 0 : tt - 2));
    }
    const unsigned short* ag = A + a_row * K + sh * 32;
    const unsigned short* bg = BT + (size_t)(n0 + sr) * K + sh * 32;
    unsigned short* aw = Al + sr * 72 + sh * 32;
    unsigned short* bw = Bl + sr * 72 + sh * 32;

    for (int k0 = 0; k0 < K; k0 += 64) {
        uint4 av0 = *(const uint4*)(ag);
        uint4 av1 = *(const uint4*)(ag + 8);
        uint4 av2 = *(const uint4*)(ag + 16);
        uint4 av3 = *(const uint4*)(ag + 24);
        uint4 bv0 = *(const uint4*)(bg);
        uint4 bv1 = *(const uint4*)(bg + 8);
        uint4 bv2 = *(const uint4*)(bg + 16);
        uint4 bv3 = *(const uint4*)(bg + 24);
        __syncthreads();  // prior frag reads complete
        *(uint4*)(aw) = av0; *(uint4*)(aw + 8) = av1;
        *(uint4*)(aw + 16) = av2; *(uint4*)(aw + 24) = av3;
        *(uint4*)(bw) = bv0; *(uint4*)(bw + 8) = bv1;
        *(uint4*)(bw + 16) = bv2; *(uint4*)(bw + 24) = bv3;
        __syncthreads();
#pragma unroll
        for (int kk = 0; kk < 2; ++kk) {
            short8_t af[4], bf[4];
#pragma unroll
            for (int mt = 0; mt < 4; ++mt)
                af[mt] = *(const short8_t*)(Al + (wr * 64 + mt * 16 + c) * 72 + kk * 32 + q * 8);
#pragma unroll
            for (int nt = 0; nt < 4; ++nt)
                bf[nt] = *(const short8_t*)(Bl + (wc * 64 + nt * 16 + c) * 72 + kk * 32 + q * 8);
#pragma unroll
            for (int mt = 0; mt < 4; ++mt)
#pragma unroll
                for (int nt = 0; nt < 4; ++nt)
                    acc[mt][nt] = __builtin_amdgcn_mfma_f32_16x16x32_bf16(
                        af[mt], bf[nt], acc[mt][nt], 0, 0, 0);
        }
        ag += 64; bg += 64;
    }

#pragma unroll
    for (int mt = 0; mt < 4; ++mt) {
        int row = m0 + wr * 64 + mt * 16 + q * 4;
#pragma unroll
        for (int nt = 0; nt < 4; ++nt) {
            int col = n0 + wc * 64 + nt * 16 + c;
            float bs = bias[col];
            if (EPI == 0) {
                float* Cf = (float*)Cout;
#pragma unroll
                for (int r = 0; r < 4; ++r)
                    Cf[(size_t)(row + r) * N + col] = acc[mt][nt][r] + bs;
            } else if (EPI == 1) {
                unsigned short* Cb = (unsigned short*)Cout;
#pragma unroll
                for (int r = 0; r < 4; ++r)
                    Cb[(size_t)(row + r) * N + col] = (unsigned short)f2bf(acc[mt][nt][r] + bs);
            } else {
                unsigned short* Fb = (unsigned short*)Cout;
#pragma unroll
                for (int r = 0; r < 4; ++r) {
                    float s = 1.f / (1.f + __expf(-(acc[mt][nt][r] + bs)));
                    unsigned short* fp = Fb + (size_t)(row + r) * 2048 + col * 4;
                    unsigned u0 = *(const unsigned*)fp;
                    unsigned u1 = *(const unsigned*)(fp + 2);
                    float f0 = bf2f(u0 & 0xffffu) * s;
                    float f1 = __uint_as_float(u0 & 0xffff0000u) * s;
                    float f2 = bf2f(u1 & 0xffffu) * s;
                    float f3 = __uint_as_float(u1 & 0xffff0000u) * s;
                    *(unsigned*)fp = f2bf(f0) | (f2bf(f1) << 16);
                    *(unsigned*)(fp + 2) = f2bf(f2) | (f2bf(f3) << 16);
                }
            }
        }
    }
}

// ---------------- LayerNorm + LeakyReLU over bf16 rows of H=2048, in place ----------------
__device__ __forceinline__ float block_sum256(float v, float* red) {
#pragma unroll
    for (int o = 32; o > 0; o >>= 1) v += __shfl_down(v, o, 64);
    int w = threadIdx.x >> 6;
    if ((threadIdx.x & 63) == 0) red[w] = v;
    __syncthreads();
    float r = red[0] + red[1] + red[2] + red[3];
    __syncthreads();
    return r;
}

__global__ __launch_bounds__(256) void ln_leaky_kernel(
    unsigned short* __restrict__ Z, const float* __restrict__ gam,
    const float* __restrict__ bet) {
    __shared__ float red[4];
    unsigned short* zr = Z + (size_t)blockIdx.x * H_;
    const int tid = threadIdx.x;
    float v[8];
    float s = 0.f;
#pragma unroll
    for (int i = 0; i < 8; ++i) { v[i] = bf2f((unsigned)zr[tid + i * 256]); s += v[i]; }
    s = block_sum256(s, red);
    float mu = s * (1.f / H_);
    float qq = 0.f;
#pragma unroll
    for (int i = 0; i < 8; ++i) { float dd = v[i] - mu; qq += dd * dd; }
    qq = block_sum256(qq, red);
    float rs = rsqrtf(qq * (1.f / H_) + 1e-5f);
#pragma unroll
    for (int i = 0; i < 8; ++i) {
        int cc = tid + i * 256;
        float y = (v[i] - mu) * rs * gam[cc] + bet[cc];
        zr[cc] = (unsigned short)f2bf(y > 0.f ? y : 0.1f * y);
    }
}

// ---------------- theta-scan v7: 16 blocks x 512 threads, 4 i-tiles/wave ----------------
// 8 waves/block (2/SIMD -> 256-VGPR budget: areg[32]=128 VGPR is affordable).
// Per wave (64 i-rows): tiles w, 8+w in REGISTERS; tile 16+w from LDS sc (wave 7
// streams); tile 24+w streamed from L2. XT double-buffered -> ONE lgkm-only
// barrier per step. XT0 init (sin=0, cos=1) -> branch-free t=0 (coup==0, r7-proven).
#define SCAN_LDS_BYTES 149760
// LDS: sc_lds [112][520]u16 @0 (116480) ; XT0 @116480 (16640) ; XT1 @133120 (16640)

__global__ __launch_bounds__(512, 1) void scan_kernel(
    const unsigned short* __restrict__ scb,  // [512][512] bf16
    const float* __restrict__ gamma,         // [32][512][512] f32
    const float* __restrict__ omega,         // [512][4]
    unsigned short* __restrict__ featb,      // [32][512][2048] bf16: sin dump (pre-g)
    float* __restrict__ msum) {              // [32][512][512] f32: sum_d theta
    extern __shared__ char smem[];
    unsigned short* sc_lds = (unsigned short*)smem;
    unsigned short* XT0 = (unsigned short*)(smem + 116480);
    unsigned short* XT1 = (unsigned short*)(smem + 133120);

    const int tid = threadIdx.x;
    const int w = tid >> 6, l = tid & 63;
    const int c = l & 15, q = l >> 4;
    const int h = c >> 3, bd = c & 7, bl = (c >> 2) & 1, d = c & 3;
    const int bglob = (int)blockIdx.x * 2 + bl;
    const int o0 = q * 4 + 2 * h;  // even row offset in tile; lane owns o0, o0+1

    // ---- XT0 init: sin rows (0-7) = 0, cos rows (8-15) = 1.0bf16 ----
    for (int idx = tid; idx < 16 * 260; idx += 512)
        ((unsigned*)XT0)[idx] = (idx < 8 * 260) ? 0u : 0x3f803f80u;
    // ---- stage LDS sc tiles 16..22 (global rows 256..367) ----
    {
        const unsigned* g32 = (const unsigned*)scb;
        unsigned* l32 = (unsigned*)sc_lds;
        for (int it = 0; it < 56; ++it) {
            int idx = it * 512 + tid;
            int row = idx >> 8, col = idx & 255;
            l32[row * 260 + col] = g32[(256 + row) * 256 + col];
        }
    }
    // ---- register tiles: rows [w*16,+16) and [128+w*16,+16) ----
    short8_t areg[32];
    {
        const unsigned short* a0 = scb + (size_t)(w * 16 + c) * 512 + q * 8;
        const unsigned short* a1 = scb + (size_t)(128 + w * 16 + c) * 512 + q * 8;
#pragma unroll
        for (int kk = 0; kk < 16; ++kk) {
            areg[kk] = *(const short8_t*)(a0 + kk * 32);
            areg[16 + kk] = *(const short8_t*)(a1 + kk * 32);
        }
    }
    const unsigned short* al2 = sc_lds + (w * 16 + c) * 520 + q * 8;               // w<7
    const unsigned short* gs2 = scb + (size_t)(256 + w * 16 + c) * 512 + q * 8;    // w==7
    const unsigned short* gs3 = scb + (size_t)(384 + w * 16 + c) * 512 + q * 8;

    const int iA0 = w * 16 + o0, iA1 = 128 + w * 16 + o0;
    const int iB0 = 256 + w * 16 + o0, iB1 = 384 + w * 16 + o0;
    const int i_ownA = ((l & 2) ? iA1 : iA0) + (l & 1);
    const int i_ownB = ((l & 2) ? iB1 : iB0) + (l & 1);
    const int ibase[4] = {iA0, iA1, iB0, iB1};

    float om[4][2], th[4][2], sn[4][2], cs[4][2];
#pragma unroll
    for (int mi = 0; mi < 4; ++mi)
#pragma unroll
        for (int rr = 0; rr < 2; ++rr) {
            om[mi][rr] = omega[(ibase[mi] + rr) * 4 + d];
            th[mi][rr] = 0.f; sn[mi][rr] = 0.f; cs[mi][rr] = 1.f;
        }
    __syncthreads();

    for (int t = 0; t < T_; ++t) {
        const unsigned short* bt = ((t & 1) ? XT1 : XT0) + c * 520 + q * 8;
        unsigned short* xw = (t & 1) ? XT0 : XT1;

        // gamma loads
        float gv[4][2];
        {
            const float* grow = gamma + ((size_t)bglob * 512 + t) * 512;
#pragma unroll
            for (int mi = 0; mi < 4; ++mi) {
                gv[mi][0] = grow[ibase[mi]];
                gv[mi][1] = grow[ibase[mi] + 1];
            }
        }

        // MFMA coupling: 4 independent 16-deep chains
        float4_t ac0 = {0.f, 0.f, 0.f, 0.f}, ac1 = {0.f, 0.f, 0.f, 0.f};
        float4_t ac2 = {0.f, 0.f, 0.f, 0.f}, ac3 = {0.f, 0.f, 0.f, 0.f};
        if (w < 7) {
#pragma unroll
            for (int kk = 0; kk < 16; ++kk) {
                short8_t bf = *(const short8_t*)(bt + kk * 32);
                short8_t a2 = *(const short8_t*)(al2 + kk * 32);
                short8_t a3 = *(const short8_t*)(gs3 + kk * 32);
                ac0 = __builtin_amdgcn_mfma_f32_16x16x32_bf16(areg[kk], bf, ac0, 0, 0, 0);
                ac1 = __builtin_amdgcn_mfma_f32_16x16x32_bf16(areg[16 + kk], bf, ac1, 0, 0, 0);
                ac2 = __builtin_amdgcn_mfma_f32_16x16x32_bf16(a2, bf, ac2, 0, 0, 0);
                ac3 = __builtin_amdgcn_mfma_f32_16x16x32_bf16(a3, bf, ac3, 0, 0, 0);
            }
        } else {
#pragma unroll
            for (int kk = 0; kk < 16; ++kk) {
                short8_t bf = *(const short8_t*)(bt + kk * 32);
                short8_t a2 = *(const short8_t*)(gs2 + kk * 32);
                short8_t a3 = *(const short8_t*)(gs3 + kk * 32);
                ac0 = __builtin_amdgcn_mfma_f32_16x16x32_bf16(areg[kk], bf, ac0, 0, 0, 0);
                ac1 = __builtin_amdgcn_mfma_f32_16x16x32_bf16(areg[16 + kk], bf, ac1, 0, 0, 0);
                ac2 = __builtin_amdgcn_mfma_f32_16x16x32_bf16(a2, bf, ac2, 0, 0, 0);
                ac3 = __builtin_amdgcn_mfma_f32_16x16x32_bf16(a3, bf, ac3, 0, 0, 0);
            }
        }

        // combine st/ct halves, theta update, hw sincos
#pragma unroll
        for (int mi = 0; mi < 4; ++mi) {
            float4_t acc = mi == 0 ? ac0 : mi == 1 ? ac1 : mi == 2 ? ac2 : ac3;
#pragma unroll
            for (int rr = 0; rr < 2; ++rr) {
                float own = h ? acc[2 + rr] : acc[rr];
                float send = h ? acc[rr] : acc[2 + rr];
                float recv = __shfl_xor(send, 8, 64);
                float Sst = h ? recv : own;
                float Sct = h ? own : recv;
                float coup = cs[mi][rr] * Sst - sn[mi][rr] * Sct;
                th[mi][rr] += 0.1f * (om[mi][rr] + gv[mi][rr] + (1.f / 512.f) * coup);
                sn[mi][rr] = sin_hw(th[mi][rr]);
                cs[mi][rr] = cos_hw(th[mi][rr]);
            }
        }

        // write new st/ct into XT[next] (bf16 pairs)
#pragma unroll
        for (int mi = 0; mi < 4; ++mi) {
            unsigned sp = f2bf(sn[mi][0]) | (f2bf(sn[mi][1]) << 16);
            unsigned cp = f2bf(cs[mi][0]) | (f2bf(cs[mi][1]) << 16);
            ((unsigned*)xw)[(bd * 520 + ibase[mi]) >> 1] = sp;
            ((unsigned*)xw)[((8 + bd) * 520 + ibase[mi]) >> 1] = cp;
        }

        // msum = sum over d (4-lane quad reduce); quad-select 2 rows/lane
        {
            float m00 = th[0][0], m01 = th[0][1], m10 = th[1][0], m11 = th[1][1];
            float m20 = th[2][0], m21 = th[2][1], m30 = th[3][0], m31 = th[3][1];
            m00 += __shfl_xor(m00, 1, 64); m00 += __shfl_xor(m00, 2, 64);
            m01 += __shfl_xor(m01, 1, 64); m01 += __shfl_xor(m01, 2, 64);
            m10 += __shfl_xor(m10, 1, 64); m10 += __shfl_xor(m10, 2, 64);
            m11 += __shfl_xor(m11, 1, 64); m11 += __shfl_xor(m11, 2, 64);
            m20 += __shfl_xor(m20, 1, 64); m20 += __shfl_xor(m20, 2, 64);
            m21 += __shfl_xor(m21, 1, 64); m21 += __shfl_xor(m21, 2, 64);
            m30 += __shfl_xor(m30, 1, 64); m30 += __shfl_xor(m30, 2, 64);
            m31 += __shfl_xor(m31, 1, 64); m31 += __shfl_xor(m31, 2, 64);
            float msA = (l & 2) ? ((l & 1) ? m11 : m10) : ((l & 1) ? m01 : m00);
            float msB = (l & 2) ? ((l & 1) ? m31 : m30) : ((l & 1) ? m21 : m20);
            float* mrow = msum + ((size_t)bglob * 512 + t) * 512;
            mrow[i_ownA] = msA;
            mrow[i_ownB] = msB;
        }

        // 4x4 lane transposes of sins -> natural feat layout, coalesced 8B stores
        {
            unsigned short* frow = featb + ((size_t)bglob * 512 + t) * 2048;
            bool bit0 = (l & 1), bit1 = (l & 2);
#pragma unroll
            for (int grp = 0; grp < 2; ++grp) {
                float A0 = sn[grp * 2][0], A1 = sn[grp * 2][1];
                float A2 = sn[grp * 2 + 1][0], A3 = sn[grp * 2 + 1][1];
                float sA = __shfl_xor(bit0 ? A0 : A1, 1, 64);
                float sB = __shfl_xor(bit0 ? A2 : A3, 1, 64);
                float B0 = bit0 ? sA : A0;
                float B1 = bit0 ? A1 : sA;
                float B2 = bit0 ? sB : A2;
                float B3 = bit0 ? A3 : sB;
                float sC = __shfl_xor(bit1 ? B0 : B2, 2, 64);
                float sD = __shfl_xor(bit1 ? B1 : B3, 2, 64);
                float c0 = bit1 ? sC : B0;
                float c1 = bit1 ? sD : B1;
                float c2 = bit1 ? B2 : sC;
                float c3 = bit1 ? B3 : sD;
                uint2 pk;
                pk.x = f2bf(c0) | (f2bf(c1) << 16);
                pk.y = f2bf(c2) | (f2bf(c3) << 16);
                *(uint2*)(frow + (grp ? i_ownB : i_ownA) * 4) = pk;
            }
        }

        // single per-step barrier: LDS (XT) ordered; global stores float freely
        asm volatile("s_waitcnt lgkmcnt(0)" ::: "memory");
        __builtin_amdgcn_s_barrier();
    }
}

// ---------------- post: g from msum, featb *= g (in place), gb = bf16(g_t) ----------------
__global__ __launch_bounds__(256) void post_kernel(
    const float* __restrict__ msum,      // [32][512][512]
    unsigned short* __restrict__ featb,  // [32][512][2048] RMW
    unsigned short* __restrict__ gb) {   // [32][512][512]
    int idx = blockIdx.x * 256 + threadIdx.x;  // 8,388,608
    int i = idx & 511;
    int t = (idx >> 9) & 511;
    int b = idx >> 18;
    int t2 = t < 2 ? 0 : t - 2;
    float m2 = msum[((size_t)b * 512 + t2) * 512 + i];
    float g = 0.5f + 0.5f * sin_hw(m2 * 0.25f);
    uint2* fp = (uint2*)(featb + ((size_t)b * 512 + t) * 2048 + i * 4);
    uint2 v = *fp;
    float f0 = bf2f(v.x & 0xffffu) * g;
    float f1 = __uint_as_float(v.x & 0xffff0000u) * g;
    float f2 = bf2f(v.y & 0xffffu) * g;
    float f3 = __uint_as_float(v.y & 0xffff0000u) * g;
    v.x = f2bf(f0) | (f2bf(f1) << 16);
    v.y = f2bf(f2) | (f2bf(f3) << 16);
    *fp = v;
    float mt = msum[((size_t)b * 512 + t) * 512 + i];
    gb[((size_t)b * 512 + t) * 512 + i] =
        (unsigned short)f2bf(0.5f + 0.5f * sin_hw(mt * 0.25f));
}

// ---------------- LIF membrane scan: cur(f32) -> spike f32 (in place) + bf16 copy ----------------
__global__ __launch_bounds__(256) void mem_scan_kernel(
    float* __restrict__ io, unsigned short* __restrict__ spb) {
    int tid = blockIdx.x * 256 + threadIdx.x;  // 65536 = B*H
    int h = tid & (H_ - 1), b = tid >> 11;
    float mem = 0.f;
    float* base = io + (size_t)b * T_ * H_ + h;
    unsigned short* sb = spb + (size_t)b * T_ * H_ + h;
    for (int t = 0; t < T_; ++t) {
        float cur = base[(size_t)t * H_];
        mem = 0.5f * mem + cur;
        float sp = 1.f / (1.f + __expf(-4.f * (mem - 1.f)));
        mem -= sp;
        base[(size_t)t * H_] = sp;
        sb[(size_t)t * H_] = (unsigned short)f2bf(sp);
    }
}

// ---------------- conv1d(k=5,pad=2) over T + log_softmax over C ----------------
__global__ __launch_bounds__(128) void conv_lsm_kernel(
    const float* __restrict__ snn, const float* __restrict__ Wc,
    const float* __restrict__ bc, float* __restrict__ out0) {
    __shared__ float sl[36 * 128];
    const int b = blockIdx.x >> 4;
    const int tt0 = (blockIdx.x & 15) * 32;
    const int co = threadIdx.x;
    for (int r = 0; r < 36; ++r) {
        int t = tt0 + r - 2;
        sl[r * 128 + co] = (t >= 0 && t < T_) ? snn[(size_t)(b * T_ + t) * 128 + co] : 0.f;
    }
    __syncthreads();
    float acc[32];
#pragma unroll
    for (int i = 0; i < 32; ++i) acc[i] = 0.f;
    for (int ci = 0; ci < 128; ++ci) {
        const float* wp = &Wc[(size_t)(co * 128 + ci) * 5];
        float w0 = wp[0], w1 = wp[1], w2 = wp[2], w3 = wp[3], w4 = wp[4];
        const float* col = &sl[ci];
        float r0 = col[0 * 128], r1 = col[1 * 128], r2 = col[2 * 128], r3 = col[3 * 128];
#pragma unroll
        for (int i = 0; i < 32; ++i) {
            float r4 = col[(i + 4) * 128];
            acc[i] += w0 * r0 + w1 * r1 + w2 * r2 + w3 * r3 + w4 * r4;
            r0 = r1; r1 = r2; r2 = r3; r3 = r4;
        }
    }
    float bco = bc[co];
    __syncthreads();
    float* cl = sl;
#pragma unroll
    for (int i = 0; i < 32; ++i) cl[i * 129 + co] = acc[i] + bco;
    __syncthreads();
    if (co < 32) {
        int t = tt0 + co;
        float mx = -3.4e38f;
        for (int cc = 0; cc < 128; ++cc) mx = fmaxf(mx, cl[co * 129 + cc]);
        float se = 0.f;
        for (int cc = 0; cc < 128; ++cc) se += __expf(cl[co * 129 + cc] - mx);
        float lse = mx + __logf(se);
        for (int cc = 0; cc < 128; ++cc)
            out0[((size_t)(b * 128 + cc)) * T_ + t] = cl[co * 129 + cc] - lse;
    }
}

// ---------------- launch ----------------
extern "C" void kernel_launch(void* const* d_in, const int* in_sizes, int n_in,
                              void* d_out, int out_size, void* d_ws, size_t ws_size,
                              hipStream_t stream) {
    (void)in_sizes; (void)n_in; (void)out_size; (void)ws_size;
    const float* x      = (const float*)d_in[0];
    const float* sc     = (const float*)d_in[1];
    const float* W_proj = (const float*)d_in[2];
    const float* b_proj = (const float*)d_in[3];
    const float* ln_g   = (const float*)d_in[4];
    const float* ln_b   = (const float*)d_in[5];
    const float* W_enc  = (const float*)d_in[6];
    const float* b_enc  = (const float*)d_in[7];
    const float* omega  = (const float*)d_in[8];
    const float* W_mask = (const float*)d_in[9];
    const float* b_mask = (const float*)d_in[10];
    const float* W_in   = (const float*)d_in[11];
    const float* b_in   = (const float*)d_in[12];
    const float* W_out  = (const float*)d_in[13];
    const float* b_out  = (const float*)d_in[14];
    const float* W_conv = (const float*)d_in[15];
    const float* b_conv = (const float*)d_in[16];

    float* out0 = (float*)d_out;                   // [B,C,T]
    float* out1 = out0 + (size_t)B_ * C_ * T_;     // [B,T,H] f32: cur -> spikes

    const int M = B_ * T_;  // 16384
    char* w = (char*)d_ws;
    float*          gamma  = (float*)w;                         // @0          33,554,432
    unsigned short* featb  = (unsigned short*)(w + 33554432);   // @33.5M      67,108,864
    float*          msum   = (float*)(w + 100663296);           // @100.7M     33,554,432
    unsigned short* gb     = (unsigned short*)(w + 134217728);  // @134.2M     16,777,216
    unsigned short* scb    = (unsigned short*)(w + 150994944);  // @151.0M        524,288
    unsigned short* wprojT = (unsigned short*)(w + 151519232);  // [2048,512]   2,097,152
    unsigned short* wencT  = (unsigned short*)(w + 153616384);  // [512,2048]   2,097,152
    unsigned short* winT   = (unsigned short*)(w + 155713536);  // [2048,2048]  8,388,608
    unsigned short* woutT  = (unsigned short*)(w + 164102144);  // [128,2048]     524,288
    unsigned short* wmT    = (unsigned short*)(w + 164626432);  // [512,512]      524,288
    unsigned short* xb  = gb;      // alias: xb dead before post writes gb
    unsigned short* Zb  = featb;   // alias: Z dead before scan writes featb
    unsigned short* spb = featb;   // alias: featb dead after G3
    float* snn_pre = gamma;        // alias: gamma dead after scan

    // conversions
    cvt_bf16_kernel<<<512, 256, 0, stream>>>(sc, (unsigned*)scb, 131072);
    cvt_bf16_kernel<<<16384, 256, 0, stream>>>(x, (unsigned*)xb, 4194304);
    cvt_T_kernel<<<dim3(64, 16), 256, 0, stream>>>(W_proj, wprojT, 512, 2048);
    cvt_T_kernel<<<dim3(16, 64), 256, 0, stream>>>(W_enc, wencT, 2048, 512);
    cvt_T_kernel<<<dim3(64, 64), 256, 0, stream>>>(W_in, winT, 2048, 2048);
    cvt_T_kernel<<<dim3(4, 64), 256, 0, stream>>>(W_out, woutT, 2048, 128);
    cvt_T_kernel<<<dim3(16, 16), 256, 0, stream>>>(W_mask, wmT, 512, 512);

    // G1: Zb = bf16(x @ W_proj + b_proj)
    gemm_bf16<1, false><<<dim3(16, 128), 256, 0, stream>>>(xb, wprojT, b_proj, Zb, M, H_, N_);
    // LN + LeakyReLU in place (bf16)
    ln_leaky_kernel<<<M, 256, 0, stream>>>(Zb, ln_g, ln_b);
    // G2: gamma(f32) = Zb @ W_enc + b_enc
    gemm_bf16<0, false><<<dim3(4, 128), 256, 0, stream>>>(Zb, wencT, b_enc, gamma, M, N_, H_);
    // theta scan -> featb (sin dump), msum
    scan_kernel<<<16, 512, SCAN_LDS_BYTES, stream>>>(scb, gamma, omega, featb, msum);
    // post: featb *= g_{t-2}, gb = bf16(g(theta_t))
    post_kernel<<<32768, 256, 0, stream>>>(msum, featb, gb);
    // deferred mask: featb *= sigmoid(gb_shift @ W_mask + b_mask)
    gemm_bf16<2, true><<<dim3(4, 128), 256, 0, stream>>>(gb, wmT, b_mask, featb, M, N_, N_);
    // G3: cur(f32, out1) = featb @ W_in + b_in
    gemm_bf16<0, false><<<dim3(16, 128), 256, 0, stream>>>(featb, winT, b_in, out1, M, H_, N_ * D_);
    // LIF membrane scan in place + bf16 spikes
    mem_scan_kernel<<<256, 256, 0, stream>>>(out1, spb);
    // G4: snn_pre(f32) = spikes @ W_out + b_out
    gemm_bf16<0, false><<<dim3(1, 128), 256, 0, stream>>>(spb, woutT, b_out, snn_pre, M, C_, H_);
    // conv1d + log_softmax -> out0
    conv_lsm_kernel<<<dim3(B_ * 16), 128, 0, stream>>>(snn_pre, W_conv, b_conv, out0);
}

// Round 11
// 3359.657 us; speedup vs baseline: 1.2894x; 1.0166x over previous
//
#include <hip/hip_runtime.h>
#include <math.h>

// Problem constants
#define B_ 32
#define T_ 512
#define N_ 512
#define D_ 4
#define H_ 2048
#define C_ 128

typedef __attribute__((ext_vector_type(8))) short short8_t;
typedef __attribute__((ext_vector_type(4))) float float4_t;

// ---------------- helpers ----------------
__device__ __forceinline__ unsigned f2bf(float x) {
    unsigned u = __float_as_uint(x);
    return (u + 0x7fffu + ((u >> 16) & 1u)) >> 16;
}
__device__ __forceinline__ float bf2f(unsigned u) {
    return __uint_as_float(u << 16);
}
#define INV2PI 0.15915494309189535f
__device__ __forceinline__ float sin_hw(float x) {
    float r = x * INV2PI;
    r -= floorf(r);
    return __builtin_amdgcn_sinf(r);
}
__device__ __forceinline__ float cos_hw(float x) {
    float r = x * INV2PI;
    r -= floorf(r);
    return __builtin_amdgcn_cosf(r);
}

// ---------------- f32 -> bf16 straight convert (packed pairs) ----------------
__global__ __launch_bounds__(256) void cvt_bf16_kernel(
    const float* __restrict__ in, unsigned* __restrict__ out, int n2) {
    int i = blockIdx.x * 256 + threadIdx.x;
    if (i < n2) out[i] = f2bf(in[2 * i]) | (f2bf(in[2 * i + 1]) << 16);
}

// ---------------- f32 [R,C] -> bf16 [C,R] transpose-convert ----------------
__global__ __launch_bounds__(256) void cvt_T_kernel(
    const float* __restrict__ in, unsigned short* __restrict__ out, int R, int C) {
    __shared__ float tl[32][33];
    const int tr = blockIdx.y * 32, tc = blockIdx.x * 32;
    const int a = threadIdx.x >> 3, b4 = (threadIdx.x & 7) * 4;
    float4 v = *(const float4*)(in + (size_t)(tr + a) * C + tc + b4);
    tl[a][b4] = v.x; tl[a][b4 + 1] = v.y; tl[a][b4 + 2] = v.z; tl[a][b4 + 3] = v.w;
    __syncthreads();
    unsigned* o32 = (unsigned*)out;
    size_t base = ((size_t)(tc + a) * R + tr + b4) >> 1;
    o32[base]     = f2bf(tl[b4][a])     | (f2bf(tl[b4 + 1][a]) << 16);
    o32[base + 1] = f2bf(tl[b4 + 2][a]) | (f2bf(tl[b4 + 3][a]) << 16);
}

// ---------------- bf16 MFMA GEMM: C[M,N] = A[M,K] @ BT[N,K]^T + bias ----------------
// 128x128 tile, BK=64, 256 threads (4 waves, 2x2), 4x4 frags of 16x16x32.
// EPI: 0 = f32 out, 1 = bf16 out, 2 = mask (sigmoid, scale featb rows in place).
// AREMAP: A row (b,t) read from (b, max(0,t-2)).
template <int EPI, bool AREMAP>
__global__ __launch_bounds__(256) void gemm_bf16(
    const unsigned short* __restrict__ A, const unsigned short* __restrict__ BT,
    const float* __restrict__ bias, void* __restrict__ Cout,
    int M, int N, int K) {
    __shared__ unsigned short Al[128 * 72];
    __shared__ unsigned short Bl[128 * 72];
    const int tid = threadIdx.x;
    const int wid = tid >> 6, l = tid & 63;
    const int c = l & 15, q = l >> 4;
    const int wr = wid >> 1, wc = wid & 1;
    const int m0 = blockIdx.y * 128, n0 = blockIdx.x * 128;
    float4_t acc[4][4];
#pragma unroll
    for (int i = 0; i < 4; ++i)
#pragma unroll
        for (int j = 0; j < 4; ++j) acc[i][j] = (float4_t){0.f, 0.f, 0.f, 0.f};

    const int sr = tid >> 1, sh = tid & 1;
    size_t a_row = (size_t)(m0 + sr);
    if (AREMAP) {
        int tt = (m0 + sr) & 511;
        a_row = (size_t)(((m0 + sr) & ~511) | (tt < 2 ? 0 : tt - 2));
    }
    const unsigned short* ag = A + a_row * K + sh * 32;
    const unsigned short* bg = BT + (size_t)(n0 + sr) * K + sh * 32;
    unsigned short* aw = Al + sr * 72 + sh * 32;
    unsigned short* bw = Bl + sr * 72 + sh * 32;

    for (int k0 = 0; k0 < K; k0 += 64) {
        uint4 av0 = *(const uint4*)(ag);
        uint4 av1 = *(const uint4*)(ag + 8);
        uint4 av2 = *(const uint4*)(ag + 16);
        uint4 av3 = *(const uint4*)(ag + 24);
        uint4 bv0 = *(const uint4*)(bg);
        uint4 bv1 = *(const uint4*)(bg + 8);
        uint4 bv2 = *(const uint4*)(bg + 16);
        uint4 bv3 = *(const uint4*)(bg + 24);
        __syncthreads();  // prior frag reads complete
        *(uint4*)(aw) = av0; *(uint4*)(aw + 8) = av1;
        *(uint4*)(aw + 16) = av2; *(uint4*)(aw + 24) = av3;
        *(uint4*)(bw) = bv0; *(uint4*)(bw + 8) = bv1;
        *(uint4*)(bw + 16) = bv2; *(uint4*)(bw + 24) = bv3;
        __syncthreads();
#pragma unroll
        for (int kk = 0; kk < 2; ++kk) {
            short8_t af[4], bf[4];
#pragma unroll
            for (int mt = 0; mt < 4; ++mt)
                af[mt] = *(const short8_t*)(Al + (wr * 64 + mt * 16 + c) * 72 + kk * 32 + q * 8);
#pragma unroll
            for (int nt = 0; nt < 4; ++nt)
                bf[nt] = *(const short8_t*)(Bl + (wc * 64 + nt * 16 + c) * 72 + kk * 32 + q * 8);
#pragma unroll
            for (int mt = 0; mt < 4; ++mt)
#pragma unroll
                for (int nt = 0; nt < 4; ++nt)
                    acc[mt][nt] = __builtin_amdgcn_mfma_f32_16x16x32_bf16(
                        af[mt], bf[nt], acc[mt][nt], 0, 0, 0);
        }
        ag += 64; bg += 64;
    }

#pragma unroll
    for (int mt = 0; mt < 4; ++mt) {
        int row = m0 + wr * 64 + mt * 16 + q * 4;
#pragma unroll
        for (int nt = 0; nt < 4; ++nt) {
            int col = n0 + wc * 64 + nt * 16 + c;
            float bs = bias[col];
            if (EPI == 0) {
                float* Cf = (float*)Cout;
#pragma unroll
                for (int r = 0; r < 4; ++r)
                    Cf[(size_t)(row + r) * N + col] = acc[mt][nt][r] + bs;
            } else if (EPI == 1) {
                unsigned short* Cb = (unsigned short*)Cout;
#pragma unroll
                for (int r = 0; r < 4; ++r)
                    Cb[(size_t)(row + r) * N + col] = (unsigned short)f2bf(acc[mt][nt][r] + bs);
            } else {
                unsigned short* Fb = (unsigned short*)Cout;
#pragma unroll
                for (int r = 0; r < 4; ++r) {
                    float s = 1.f / (1.f + __expf(-(acc[mt][nt][r] + bs)));
                    unsigned short* fp = Fb + (size_t)(row + r) * 2048 + col * 4;
                    unsigned u0 = *(const unsigned*)fp;
                    unsigned u1 = *(const unsigned*)(fp + 2);
                    float f0 = bf2f(u0 & 0xffffu) * s;
                    float f1 = __uint_as_float(u0 & 0xffff0000u) * s;
                    float f2 = bf2f(u1 & 0xffffu) * s;
                    float f3 = __uint_as_float(u1 & 0xffff0000u) * s;
                    *(unsigned*)fp = f2bf(f0) | (f2bf(f1) << 16);
                    *(unsigned*)(fp + 2) = f2bf(f2) | (f2bf(f3) << 16);
                }
            }
        }
    }
}

// ---------------- LayerNorm + LeakyReLU over bf16 rows of H=2048, in place ----------------
__device__ __forceinline__ float block_sum256(float v, float* red) {
#pragma unroll
    for (int o = 32; o > 0; o >>= 1) v += __shfl_down(v, o, 64);
    int w = threadIdx.x >> 6;
    if ((threadIdx.x & 63) == 0) red[w] = v;
    __syncthreads();
    float r = red[0] + red[1] + red[2] + red[3];
    __syncthreads();
    return r;
}

__global__ __launch_bounds__(256) void ln_leaky_kernel(
    unsigned short* __restrict__ Z, const float* __restrict__ gam,
    const float* __restrict__ bet) {
    __shared__ float red[4];
    unsigned short* zr = Z + (size_t)blockIdx.x * H_;
    const int tid = threadIdx.x;
    float v[8];
    float s = 0.f;
#pragma unroll
    for (int i = 0; i < 8; ++i) { v[i] = bf2f((unsigned)zr[tid + i * 256]); s += v[i]; }
    s = block_sum256(s, red);
    float mu = s * (1.f / H_);
    float qq = 0.f;
#pragma unroll
    for (int i = 0; i < 8; ++i) { float dd = v[i] - mu; qq += dd * dd; }
    qq = block_sum256(qq, red);
    float rs = rsqrtf(qq * (1.f / H_) + 1e-5f);
#pragma unroll
    for (int i = 0; i < 8; ++i) {
        int cc = tid + i * 256;
        float y = (v[i] - mu) * rs * gam[cc] + bet[cc];
        zr[cc] = (unsigned short)f2bf(y > 0.f ? y : 0.1f * y);
    }
}

// ---------------- theta-scan v8: r10 skeleton + batched stream + early barrier ----------------
// 16 blocks x 512 threads (8 waves, 2/SIMD, 256-VGPR budget via waves_per_eu(2,2)).
// Per wave (64 i-rows): tiles w, 8+w in REGISTERS; tile 16+w from LDS sc (wave 7
// streams); tile 24+w batch-streamed into sreg[16] each step (one L2 round-trip).
// Step order: MFMA -> theta/sincos -> XT[next] write -> lgkm barrier -> tail
// (msum reduce, transpose, global stores) AFTER the barrier (off the critical path).
#define SCAN_LDS_BYTES 149760
// LDS: sc_lds [112][520]u16 @0 (116480) ; XT0 @116480 (16640) ; XT1 @133120 (16640)

__global__ __launch_bounds__(512) __attribute__((amdgpu_waves_per_eu(2, 2)))
void scan_kernel(
    const unsigned short* __restrict__ scb,  // [512][512] bf16
    const float* __restrict__ gamma,         // [32][512][512] f32
    const float* __restrict__ omega,         // [512][4]
    unsigned short* __restrict__ featb,      // [32][512][2048] bf16: sin dump (pre-g)
    float* __restrict__ msum) {              // [32][512][512] f32: sum_d theta
    extern __shared__ char smem[];
    unsigned short* sc_lds = (unsigned short*)smem;
    unsigned short* XT0 = (unsigned short*)(smem + 116480);
    unsigned short* XT1 = (unsigned short*)(smem + 133120);

    const int tid = threadIdx.x;
    const int w = tid >> 6, l = tid & 63;
    const int c = l & 15, q = l >> 4;
    const int h = c >> 3, bd = c & 7, bl = (c >> 2) & 1, d = c & 3;
    const int bglob = (int)blockIdx.x * 2 + bl;
    const int o0 = q * 4 + 2 * h;  // even row offset in tile; lane owns o0, o0+1

    // ---- XT0 init: sin rows (0-7) = 0, cos rows (8-15) = 1.0bf16 ----
    for (int idx = tid; idx < 16 * 260; idx += 512)
        ((unsigned*)XT0)[idx] = (idx < 8 * 260) ? 0u : 0x3f803f80u;
    // ---- stage LDS sc tiles 16..22 (global rows 256..367) ----
    {
        const unsigned* g32 = (const unsigned*)scb;
        unsigned* l32 = (unsigned*)sc_lds;
        for (int it = 0; it < 56; ++it) {
            int idx = it * 512 + tid;
            int row = idx >> 8, col = idx & 255;
            l32[row * 260 + col] = g32[(256 + row) * 256 + col];
        }
    }
    // ---- register tiles: rows [w*16,+16) and [128+w*16,+16) ----
    short8_t areg[32];
    {
        const unsigned short* a0 = scb + (size_t)(w * 16 + c) * 512 + q * 8;
        const unsigned short* a1 = scb + (size_t)(128 + w * 16 + c) * 512 + q * 8;
#pragma unroll
        for (int kk = 0; kk < 16; ++kk) {
            areg[kk] = *(const short8_t*)(a0 + kk * 32);
            areg[16 + kk] = *(const short8_t*)(a1 + kk * 32);
        }
    }
    const unsigned short* al2 = sc_lds + (w * 16 + c) * 520 + q * 8;               // w<7
    const unsigned short* gs2 = scb + (size_t)(256 + w * 16 + c) * 512 + q * 8;    // w==7
    const unsigned short* gs3 = scb + (size_t)(384 + w * 16 + c) * 512 + q * 8;

    const int iA0 = w * 16 + o0, iA1 = 128 + w * 16 + o0;
    const int iB0 = 256 + w * 16 + o0, iB1 = 384 + w * 16 + o0;
    const int i_ownA = ((l & 2) ? iA1 : iA0) + (l & 1);
    const int i_ownB = ((l & 2) ? iB1 : iB0) + (l & 1);
    const int ibase[4] = {iA0, iA1, iB0, iB1};

    float om[4][2], th[4][2], sn[4][2], cs[4][2];
#pragma unroll
    for (int mi = 0; mi < 4; ++mi)
#pragma unroll
        for (int rr = 0; rr < 2; ++rr) {
            om[mi][rr] = omega[(ibase[mi] + rr) * 4 + d];
            th[mi][rr] = 0.f; sn[mi][rr] = 0.f; cs[mi][rr] = 1.f;
        }
    __syncthreads();

    for (int t = 0; t < T_; ++t) {
        const unsigned short* bt = ((t & 1) ? XT1 : XT0) + c * 520 + q * 8;
        unsigned short* xw = (t & 1) ? XT0 : XT1;

        // gamma loads
        float gv[4][2];
        {
            const float* grow = gamma + ((size_t)bglob * 512 + t) * 512;
#pragma unroll
            for (int mi = 0; mi < 4; ++mi) {
                gv[mi][0] = grow[ibase[mi]];
                gv[mi][1] = grow[ibase[mi] + 1];
            }
        }
        // batch-issue the streamed tile's 16 loads (one L2 round-trip, not 16)
        uint4 sreg[16];
#pragma unroll
        for (int kk = 0; kk < 16; ++kk)
            sreg[kk] = *(const uint4*)(gs3 + kk * 32);

        // MFMA coupling: 4 independent 16-deep chains
        float4_t ac0 = {0.f, 0.f, 0.f, 0.f}, ac1 = {0.f, 0.f, 0.f, 0.f};
        float4_t ac2 = {0.f, 0.f, 0.f, 0.f}, ac3 = {0.f, 0.f, 0.f, 0.f};
        if (w < 7) {
#pragma unroll
            for (int kk = 0; kk < 16; ++kk) {
                short8_t bf = *(const short8_t*)(bt + kk * 32);
                short8_t a2 = *(const short8_t*)(al2 + kk * 32);
                ac0 = __builtin_amdgcn_mfma_f32_16x16x32_bf16(areg[kk], bf, ac0, 0, 0, 0);
                ac1 = __builtin_amdgcn_mfma_f32_16x16x32_bf16(areg[16 + kk], bf, ac1, 0, 0, 0);
                ac2 = __builtin_amdgcn_mfma_f32_16x16x32_bf16(a2, bf, ac2, 0, 0, 0);
                ac3 = __builtin_amdgcn_mfma_f32_16x16x32_bf16(
                    __builtin_bit_cast(short8_t, sreg[kk]), bf, ac3, 0, 0, 0);
            }
        } else {
#pragma unroll
            for (int kk = 0; kk < 16; ++kk) {
                short8_t bf = *(const short8_t*)(bt + kk * 32);
                short8_t a2 = *(const short8_t*)(gs2 + kk * 32);
                ac0 = __builtin_amdgcn_mfma_f32_16x16x32_bf16(areg[kk], bf, ac0, 0, 0, 0);
                ac1 = __builtin_amdgcn_mfma_f32_16x16x32_bf16(areg[16 + kk], bf, ac1, 0, 0, 0);
                ac2 = __builtin_amdgcn_mfma_f32_16x16x32_bf16(a2, bf, ac2, 0, 0, 0);
                ac3 = __builtin_amdgcn_mfma_f32_16x16x32_bf16(
                    __builtin_bit_cast(short8_t, sreg[kk]), bf, ac3, 0, 0, 0);
            }
        }

        // combine st/ct halves, theta update, hw sincos
#pragma unroll
        for (int mi = 0; mi < 4; ++mi) {
            float4_t acc = mi == 0 ? ac0 : mi == 1 ? ac1 : mi == 2 ? ac2 : ac3;
#pragma unroll
            for (int rr = 0; rr < 2; ++rr) {
                float own = h ? acc[2 + rr] : acc[rr];
                float send = h ? acc[rr] : acc[2 + rr];
                float recv = __shfl_xor(send, 8, 64);
                float Sst = h ? recv : own;
                float Sct = h ? own : recv;
                float coup = cs[mi][rr] * Sst - sn[mi][rr] * Sct;
                th[mi][rr] += 0.1f * (om[mi][rr] + gv[mi][rr] + (1.f / 512.f) * coup);
                sn[mi][rr] = sin_hw(th[mi][rr]);
                cs[mi][rr] = cos_hw(th[mi][rr]);
            }
        }

        // write new st/ct into XT[next] (bf16 pairs) -- then barrier IMMEDIATELY
#pragma unroll
        for (int mi = 0; mi < 4; ++mi) {
            unsigned sp = f2bf(sn[mi][0]) | (f2bf(sn[mi][1]) << 16);
            unsigned cp = f2bf(cs[mi][0]) | (f2bf(cs[mi][1]) << 16);
            ((unsigned*)xw)[(bd * 520 + ibase[mi]) >> 1] = sp;
            ((unsigned*)xw)[((8 + bd) * 520 + ibase[mi]) >> 1] = cp;
        }
        asm volatile("s_waitcnt lgkmcnt(0)" ::: "memory");
        __builtin_amdgcn_s_barrier();

        // ---- tail AFTER the barrier (registers + global only; off critical path) ----
        // msum = sum over d (4-lane quad reduce); quad-select 2 rows/lane
        {
            float m00 = th[0][0], m01 = th[0][1], m10 = th[1][0], m11 = th[1][1];
            float m20 = th[2][0], m21 = th[2][1], m30 = th[3][0], m31 = th[3][1];
            m00 += __shfl_xor(m00, 1, 64); m00 += __shfl_xor(m00, 2, 64);
            m01 += __shfl_xor(m01, 1, 64); m01 += __shfl_xor(m01, 2, 64);
            m10 += __shfl_xor(m10, 1, 64); m10 += __shfl_xor(m10, 2, 64);
            m11 += __shfl_xor(m11, 1, 64); m11 += __shfl_xor(m11, 2, 64);
            m20 += __shfl_xor(m20, 1, 64); m20 += __shfl_xor(m20, 2, 64);
            m21 += __shfl_xor(m21, 1, 64); m21 += __shfl_xor(m21, 2, 64);
            m30 += __shfl_xor(m30, 1, 64); m30 += __shfl_xor(m30, 2, 64);
            m31 += __shfl_xor(m31, 1, 64); m31 += __shfl_xor(m31, 2, 64);
            float msA = (l & 2) ? ((l & 1) ? m11 : m10) : ((l & 1) ? m01 : m00);
            float msB = (l & 2) ? ((l & 1) ? m31 : m30) : ((l & 1) ? m21 : m20);
            float* mrow = msum + ((size_t)bglob * 512 + t) * 512;
            mrow[i_ownA] = msA;
            mrow[i_ownB] = msB;
        }
        // 4x4 lane transposes of sins -> natural feat layout, coalesced 8B stores
        {
            unsigned short* frow = featb + ((size_t)bglob * 512 + t) * 2048;
            bool bit0 = (l & 1), bit1 = (l & 2);
#pragma unroll
            for (int grp = 0; grp < 2; ++grp) {
                float A0 = sn[grp * 2][0], A1 = sn[grp * 2][1];
                float A2 = sn[grp * 2 + 1][0], A3 = sn[grp * 2 + 1][1];
                float sA = __shfl_xor(bit0 ? A0 : A1, 1, 64);
                float sB = __shfl_xor(bit0 ? A2 : A3, 1, 64);
                float B0 = bit0 ? sA : A0;
                float B1 = bit0 ? A1 : sA;
                float B2 = bit0 ? sB : A2;
                float B3 = bit0 ? A3 : sB;
                float sC = __shfl_xor(bit1 ? B0 : B2, 2, 64);
                float sD = __shfl_xor(bit1 ? B1 : B3, 2, 64);
                float c0 = bit1 ? sC : B0;
                float c1 = bit1 ? sD : B1;
                float c2 = bit1 ? B2 : sC;
                float c3 = bit1 ? B3 : sD;
                uint2 pk;
                pk.x = f2bf(c0) | (f2bf(c1) << 16);
                pk.y = f2bf(c2) | (f2bf(c3) << 16);
                *(uint2*)(frow + (grp ? i_ownB : i_ownA) * 4) = pk;
            }
        }
    }
}

// ---------------- post: g from msum, featb *= g (in place), gb = bf16(g_t) ----------------
__global__ __launch_bounds__(256) void post_kernel(
    const float* __restrict__ msum,      // [32][512][512]
    unsigned short* __restrict__ featb,  // [32][512][2048] RMW
    unsigned short* __restrict__ gb) {   // [32][512][512]
    int idx = blockIdx.x * 256 + threadIdx.x;  // 8,388,608
    int i = idx & 511;
    int t = (idx >> 9) & 511;
    int b = idx >> 18;
    int t2 = t < 2 ? 0 : t - 2;
    float m2 = msum[((size_t)b * 512 + t2) * 512 + i];
    float g = 0.5f + 0.5f * sin_hw(m2 * 0.25f);
    uint2* fp = (uint2*)(featb + ((size_t)b * 512 + t) * 2048 + i * 4);
    uint2 v = *fp;
    float f0 = bf2f(v.x & 0xffffu) * g;
    float f1 = __uint_as_float(v.x & 0xffff0000u) * g;
    float f2 = bf2f(v.y & 0xffffu) * g;
    float f3 = __uint_as_float(v.y & 0xffff0000u) * g;
    v.x = f2bf(f0) | (f2bf(f1) << 16);
    v.y = f2bf(f2) | (f2bf(f3) << 16);
    *fp = v;
    float mt = msum[((size_t)b * 512 + t) * 512 + i];
    gb[((size_t)b * 512 + t) * 512 + i] =
        (unsigned short)f2bf(0.5f + 0.5f * sin_hw(mt * 0.25f));
}

// ---------------- LIF membrane scan: cur(f32) -> spike f32 (in place) + bf16 copy ----------------
__global__ __launch_bounds__(256) void mem_scan_kernel(
    float* __restrict__ io, unsigned short* __restrict__ spb) {
    int tid = blockIdx.x * 256 + threadIdx.x;  // 65536 = B*H
    int h = tid & (H_ - 1), b = tid >> 11;
    float mem = 0.f;
    float* base = io + (size_t)b * T_ * H_ + h;
    unsigned short* sb = spb + (size_t)b * T_ * H_ + h;
    for (int t = 0; t < T_; ++t) {
        float cur = base[(size_t)t * H_];
        mem = 0.5f * mem + cur;
        float sp = 1.f / (1.f + __expf(-4.f * (mem - 1.f)));
        mem -= sp;
        base[(size_t)t * H_] = sp;
        sb[(size_t)t * H_] = (unsigned short)f2bf(sp);
    }
}

// ---------------- conv1d(k=5,pad=2) over T + log_softmax over C ----------------
__global__ __launch_bounds__(128) void conv_lsm_kernel(
    const float* __restrict__ snn, const float* __restrict__ Wc,
    const float* __restrict__ bc, float* __restrict__ out0) {
    __shared__ float sl[36 * 128];
    const int b = blockIdx.x >> 4;
    const int tt0 = (blockIdx.x & 15) * 32;
    const int co = threadIdx.x;
    for (int r = 0; r < 36; ++r) {
        int t = tt0 + r - 2;
        sl[r * 128 + co] = (t >= 0 && t < T_) ? snn[(size_t)(b * T_ + t) * 128 + co] : 0.f;
    }
    __syncthreads();
    float acc[32];
#pragma unroll
    for (int i = 0; i < 32; ++i) acc[i] = 0.f;
    for (int ci = 0; ci < 128; ++ci) {
        const float* wp = &Wc[(size_t)(co * 128 + ci) * 5];
        float w0 = wp[0], w1 = wp[1], w2 = wp[2], w3 = wp[3], w4 = wp[4];
        const float* col = &sl[ci];
        float r0 = col[0 * 128], r1 = col[1 * 128], r2 = col[2 * 128], r3 = col[3 * 128];
#pragma unroll
        for (int i = 0; i < 32; ++i) {
            float r4 = col[(i + 4) * 128];
            acc[i] += w0 * r0 + w1 * r1 + w2 * r2 + w3 * r3 + w4 * r4;
            r0 = r1; r1 = r2; r2 = r3; r3 = r4;
        }
    }
    float bco = bc[co];
    __syncthreads();
    float* cl = sl;
#pragma unroll
    for (int i = 0; i < 32; ++i) cl[i * 129 + co] = acc[i] + bco;
    __syncthreads();
    if (co < 32) {
        int t = tt0 + co;
        float mx = -3.4e38f;
        for (int cc = 0; cc < 128; ++cc) mx = fmaxf(mx, cl[co * 129 + cc]);
        float se = 0.f;
        for (int cc = 0; cc < 128; ++cc) se += __expf(cl[co * 129 + cc] - mx);
        float lse = mx + __logf(se);
        for (int cc = 0; cc < 128; ++cc)
            out0[((size_t)(b * 128 + cc)) * T_ + t] = cl[co * 129 + cc] - lse;
    }
}

// ---------------- launch ----------------
extern "C" void kernel_launch(void* const* d_in, const int* in_sizes, int n_in,
                              void* d_out, int out_size, void* d_ws, size_t ws_size,
                              hipStream_t stream) {
    (void)in_sizes; (void)n_in; (void)out_size; (void)ws_size;
    const float* x      = (const float*)d_in[0];
    const float* sc     = (const float*)d_in[1];
    const float* W_proj = (const float*)d_in[2];
    const float* b_proj = (const float*)d_in[3];
    const float* ln_g   = (const float*)d_in[4];
    const float* ln_b   = (const float*)d_in[5];
    const float* W_enc  = (const float*)d_in[6];
    const float* b_enc  = (const float*)d_in[7];
    const float* omega  = (const float*)d_in[8];
    const float* W_mask = (const float*)d_in[9];
    const float* b_mask = (const float*)d_in[10];
    const float* W_in   = (const float*)d_in[11];
    const float* b_in   = (const float*)d_in[12];
    const float* W_out  = (const float*)d_in[13];
    const float* b_out  = (const float*)d_in[14];
    const float* W_conv = (const float*)d_in[15];
    const float* b_conv = (const float*)d_in[16];

    float* out0 = (float*)d_out;                   // [B,C,T]
    float* out1 = out0 + (size_t)B_ * C_ * T_;     // [B,T,H] f32: cur -> spikes

    const int M = B_ * T_;  // 16384
    char* w = (char*)d_ws;
    float*          gamma  = (float*)w;                         // @0          33,554,432
    unsigned short* featb  = (unsigned short*)(w + 33554432);   // @33.5M      67,108,864
    float*          msum   = (float*)(w + 100663296);           // @100.7M     33,554,432
    unsigned short* gb     = (unsigned short*)(w + 134217728);  // @134.2M     16,777,216
    unsigned short* scb    = (unsigned short*)(w + 150994944);  // @151.0M        524,288
    unsigned short* wprojT = (unsigned short*)(w + 151519232);  // [2048,512]   2,097,152
    unsigned short* wencT  = (unsigned short*)(w + 153616384);  // [512,2048]   2,097,152
    unsigned short* winT   = (unsigned short*)(w + 155713536);  // [2048,2048]  8,388,608
    unsigned short* woutT  = (unsigned short*)(w + 164102144);  // [128,2048]     524,288
    unsigned short* wmT    = (unsigned short*)(w + 164626432);  // [512,512]      524,288
    unsigned short* xb  = gb;      // alias: xb dead before post writes gb
    unsigned short* Zb  = featb;   // alias: Z dead before scan writes featb
    unsigned short* spb = featb;   // alias: featb dead after G3
    float* snn_pre = gamma;        // alias: gamma dead after scan

    // conversions
    cvt_bf16_kernel<<<512, 256, 0, stream>>>(sc, (unsigned*)scb, 131072);
    cvt_bf16_kernel<<<16384, 256, 0, stream>>>(x, (unsigned*)xb, 4194304);
    cvt_T_kernel<<<dim3(64, 16), 256, 0, stream>>>(W_proj, wprojT, 512, 2048);
    cvt_T_kernel<<<dim3(16, 64), 256, 0, stream>>>(W_enc, wencT, 2048, 512);
    cvt_T_kernel<<<dim3(64, 64), 256, 0, stream>>>(W_in, winT, 2048, 2048);
    cvt_T_kernel<<<dim3(4, 64), 256, 0, stream>>>(W_out, woutT, 2048, 128);
    cvt_T_kernel<<<dim3(16, 16), 256, 0, stream>>>(W_mask, wmT, 512, 512);

    // G1: Zb = bf16(x @ W_proj + b_proj)
    gemm_bf16<1, false><<<dim3(16, 128), 256, 0, stream>>>(xb, wprojT, b_proj, Zb, M, H_, N_);
    // LN + LeakyReLU in place (bf16)
    ln_leaky_kernel<<<M, 256, 0, stream>>>(Zb, ln_g, ln_b);
    // G2: gamma(f32) = Zb @ W_enc + b_enc
    gemm_bf16<0, false><<<dim3(4, 128), 256, 0, stream>>>(Zb, wencT, b_enc, gamma, M, N_, H_);
    // theta scan -> featb (sin dump), msum
    scan_kernel<<<16, 512, SCAN_LDS_BYTES, stream>>>(scb, gamma, omega, featb, msum);
    // post: featb *= g_{t-2}, gb = bf16(g(theta_t))
    post_kernel<<<32768, 256, 0, stream>>>(msum, featb, gb);
    // deferred mask: featb *= sigmoid(gb_shift @ W_mask + b_mask)
    gemm_bf16<2, true><<<dim3(4, 128), 256, 0, stream>>>(gb, wmT, b_mask, featb, M, N_, N_);
    // G3: cur(f32, out1) = featb @ W_in + b_in
    gemm_bf16<0, false><<<dim3(16, 128), 256, 0, stream>>>(featb, winT, b_in, out1, M, H_, N_ * D_);
    // LIF membrane scan in place + bf16 spikes
    mem_scan_kernel<<<256, 256, 0, stream>>>(out1, spb);
    // G4: snn_pre(f32) = spikes @ W_out + b_out
    gemm_bf16<0, false><<<dim3(1, 128), 256, 0, stream>>>(spb, woutT, b_out, snn_pre, M, C_, H_);
    // conv1d + log_softmax -> out0
    conv_lsm_kernel<<<dim3(B_ * 16), 128, 0, stream>>>(snn_pre, W_conv, b_conv, out0);
}

// Round 12
// 2496.898 us; speedup vs baseline: 1.7349x; 1.3455x over previous
//
#include <hip/hip_runtime.h>
#include <math.h>

// Problem constants
#define B_ 32
#define T_ 512
#define N_ 512
#define D_ 4
#define H_ 2048
#define C_ 128

typedef __attribute__((ext_vector_type(8))) short short8_t;
typedef __attribute__((ext_vector_type(4))) float float4_t;

// ---------------- helpers ----------------
__device__ __forceinline__ unsigned f2bf(float x) {
    unsigned u = __float_as_uint(x);
    return (u + 0x7fffu + ((u >> 16) & 1u)) >> 16;
}
__device__ __forceinline__ float bf2f(unsigned u) {
    return __uint_as_float(u << 16);
}
#define INV2PI 0.15915494309189535f
__device__ __forceinline__ float sin_hw(float x) {
    float r = x * INV2PI;
    r -= floorf(r);
    return __builtin_amdgcn_sinf(r);
}
__device__ __forceinline__ float cos_hw(float x) {
    float r = x * INV2PI;
    r -= floorf(r);
    return __builtin_amdgcn_cosf(r);
}

// ---------------- f32 -> bf16 straight convert (packed pairs) ----------------
__global__ __launch_bounds__(256) void cvt_bf16_kernel(
    const float* __restrict__ in, unsigned* __restrict__ out, int n2) {
    int i = blockIdx.x * 256 + threadIdx.x;
    if (i < n2) out[i] = f2bf(in[2 * i]) | (f2bf(in[2 * i + 1]) << 16);
}

// ---------------- f32 [R,C] -> bf16 [C,R] transpose-convert ----------------
__global__ __launch_bounds__(256) void cvt_T_kernel(
    const float* __restrict__ in, unsigned short* __restrict__ out, int R, int C) {
    __shared__ float tl[32][33];
    const int tr = blockIdx.y * 32, tc = blockIdx.x * 32;
    const int a = threadIdx.x >> 3, b4 = (threadIdx.x & 7) * 4;
    float4 v = *(const float4*)(in + (size_t)(tr + a) * C + tc + b4);
    tl[a][b4] = v.x; tl[a][b4 + 1] = v.y; tl[a][b4 + 2] = v.z; tl[a][b4 + 3] = v.w;
    __syncthreads();
    unsigned* o32 = (unsigned*)out;
    size_t base = ((size_t)(tc + a) * R + tr + b4) >> 1;
    o32[base]     = f2bf(tl[b4][a])     | (f2bf(tl[b4 + 1][a]) << 16);
    o32[base + 1] = f2bf(tl[b4 + 2][a]) | (f2bf(tl[b4 + 3][a]) << 16);
}

// ---------------- bf16 MFMA GEMM: C[M,N] = A[M,K] @ BT[N,K]^T + bias ----------------
// 128x128 tile, BK=64, 256 threads (4 waves, 2x2), 4x4 frags of 16x16x32.
// EPI: 0 = f32 out, 1 = bf16 out, 2 = mask (sigmoid, scale featb rows in place).
// AREMAP: A row (b,t) read from (b, max(0,t-2)).
template <int EPI, bool AREMAP>
__global__ __launch_bounds__(256) void gemm_bf16(
    const unsigned short* __restrict__ A, const unsigned short* __restrict__ BT,
    const float* __restrict__ bias, void* __restrict__ Cout,
    int M, int N, int K) {
    __shared__ unsigned short Al[128 * 72];
    __shared__ unsigned short Bl[128 * 72];
    const int tid = threadIdx.x;
    const int wid = tid >> 6, l = tid & 63;
    const int c = l & 15, q = l >> 4;
    const int wr = wid >> 1, wc = wid & 1;
    const int m0 = blockIdx.y * 128, n0 = blockIdx.x * 128;
    float4_t acc[4][4];
#pragma unroll
    for (int i = 0; i < 4; ++i)
#pragma unroll
        for (int j = 0; j < 4; ++j) acc[i][j] = (float4_t){0.f, 0.f, 0.f, 0.f};

    const int sr = tid >> 1, sh = tid & 1;
    size_t a_row = (size_t)(m0 + sr);
    if (AREMAP) {
        int tt = (m0 + sr) & 511;
        a_row = (size_t)(((m0 + sr) & ~511) | (tt < 2 ? 0 : tt - 2));
    }
    const unsigned short* ag = A + a_row * K + sh * 32;
    const unsigned short* bg = BT + (size_t)(n0 + sr) * K + sh * 32;
    unsigned short* aw = Al + sr * 72 + sh * 32;
    unsigned short* bw = Bl + sr * 72 + sh * 32;

    for (int k0 = 0; k0 < K; k0 += 64) {
        uint4 av0 = *(const uint4*)(ag);
        uint4 av1 = *(const uint4*)(ag + 8);
        uint4 av2 = *(const uint4*)(ag + 16);
        uint4 av3 = *(const uint4*)(ag + 24);
        uint4 bv0 = *(const uint4*)(bg);
        uint4 bv1 = *(const uint4*)(bg + 8);
        uint4 bv2 = *(const uint4*)(bg + 16);
        uint4 bv3 = *(const uint4*)(bg + 24);
        __syncthreads();  // prior frag reads complete
        *(uint4*)(aw) = av0; *(uint4*)(aw + 8) = av1;
        *(uint4*)(aw + 16) = av2; *(uint4*)(aw + 24) = av3;
        *(uint4*)(bw) = bv0; *(uint4*)(bw + 8) = bv1;
        *(uint4*)(bw + 16) = bv2; *(uint4*)(bw + 24) = bv3;
        __syncthreads();
#pragma unroll
        for (int kk = 0; kk < 2; ++kk) {
            short8_t af[4], bf[4];
#pragma unroll
            for (int mt = 0; mt < 4; ++mt)
                af[mt] = *(const short8_t*)(Al + (wr * 64 + mt * 16 + c) * 72 + kk * 32 + q * 8);
#pragma unroll
            for (int nt = 0; nt < 4; ++nt)
                bf[nt] = *(const short8_t*)(Bl + (wc * 64 + nt * 16 + c) * 72 + kk * 32 + q * 8);
#pragma unroll
            for (int mt = 0; mt < 4; ++mt)
#pragma unroll
                for (int nt = 0; nt < 4; ++nt)
                    acc[mt][nt] = __builtin_amdgcn_mfma_f32_16x16x32_bf16(
                        af[mt], bf[nt], acc[mt][nt], 0, 0, 0);
        }
        ag += 64; bg += 64;
    }

#pragma unroll
    for (int mt = 0; mt < 4; ++mt) {
        int row = m0 + wr * 64 + mt * 16 + q * 4;
#pragma unroll
        for (int nt = 0; nt < 4; ++nt) {
            int col = n0 + wc * 64 + nt * 16 + c;
            float bs = bias[col];
            if (EPI == 0) {
                float* Cf = (float*)Cout;
#pragma unroll
                for (int r = 0; r < 4; ++r)
                    Cf[(size_t)(row + r) * N + col] = acc[mt][nt][r] + bs;
            } else if (EPI == 1) {
                unsigned short* Cb = (unsigned short*)Cout;
#pragma unroll
                for (int r = 0; r < 4; ++r)
                    Cb[(size_t)(row + r) * N + col] = (unsigned short)f2bf(acc[mt][nt][r] + bs);
            } else {
                unsigned short* Fb = (unsigned short*)Cout;
#pragma unroll
                for (int r = 0; r < 4; ++r) {
                    float s = 1.f / (1.f + __expf(-(acc[mt][nt][r] + bs)));
                    unsigned short* fp = Fb + (size_t)(row + r) * 2048 + col * 4;
                    unsigned u0 = *(const unsigned*)fp;
                    unsigned u1 = *(const unsigned*)(fp + 2);
                    float f0 = bf2f(u0 & 0xffffu) * s;
                    float f1 = __uint_as_float(u0 & 0xffff0000u) * s;
                    float f2 = bf2f(u1 & 0xffffu) * s;
                    float f3 = __uint_as_float(u1 & 0xffff0000u) * s;
                    *(unsigned*)fp = f2bf(f0) | (f2bf(f1) << 16);
                    *(unsigned*)(fp + 2) = f2bf(f2) | (f2bf(f3) << 16);
                }
            }
        }
    }
}

// ---------------- LayerNorm + LeakyReLU over bf16 rows of H=2048, in place ----------------
__device__ __forceinline__ float block_sum256(float v, float* red) {
#pragma unroll
    for (int o = 32; o > 0; o >>= 1) v += __shfl_down(v, o, 64);
    int w = threadIdx.x >> 6;
    if ((threadIdx.x & 63) == 0) red[w] = v;
    __syncthreads();
    float r = red[0] + red[1] + red[2] + red[3];
    __syncthreads();
    return r;
}

__global__ __launch_bounds__(256) void ln_leaky_kernel(
    unsigned short* __restrict__ Z, const float* __restrict__ gam,
    const float* __restrict__ bet) {
    __shared__ float red[4];
    unsigned short* zr = Z + (size_t)blockIdx.x * H_;
    const int tid = threadIdx.x;
    float v[8];
    float s = 0.f;
#pragma unroll
    for (int i = 0; i < 8; ++i) { v[i] = bf2f((unsigned)zr[tid + i * 256]); s += v[i]; }
    s = block_sum256(s, red);
    float mu = s * (1.f / H_);
    float qq = 0.f;
#pragma unroll
    for (int i = 0; i < 8; ++i) { float dd = v[i] - mu; qq += dd * dd; }
    qq = block_sum256(qq, red);
    float rs = rsqrtf(qq * (1.f / H_) + 1e-5f);
#pragma unroll
    for (int i = 0; i < 8; ++i) {
        int cc = tid + i * 256;
        float y = (v[i] - mu) * rs * gam[cc] + bet[cc];
        zr[cc] = (unsigned short)f2bf(y > 0.f ? y : 0.1f * y);
    }
}

// ---------------- theta-scan v9: 32 blocks x 512 threads, ONE batch per block ----------------
// Key: the recurrence is separable over (b,d) — msum (the only cross-d term) is consumed
// post-scan, so blocks never communicate. 32 blocks = 32 CUs: per-CU VALU/stores/gamma
// HALVE vs the 2-batch layout (4 thetas/lane), while sc traffic per CU is unchanged.
// B operand: cols bd and 4+bd hold DUPLICATED st (same d=bd&3); the bl=(c>>2)&1 bit now
// selects the row within each row-pair (row = q*4 + 2h + bl). XT pack via shfl_xor(4).
#define SCAN_LDS_BYTES 149760
// LDS: sc_lds [112][520]u16 @0 (116480) ; XT0 @116480 (16640) ; XT1 @133120 (16640)

__global__ __launch_bounds__(512) __attribute__((amdgpu_waves_per_eu(2, 2)))
void scan_kernel(
    const unsigned short* __restrict__ scb,  // [512][512] bf16
    const float* __restrict__ gamma,         // [32][512][512] f32
    const float* __restrict__ omega,         // [512][4]
    unsigned short* __restrict__ featb,      // [32][512][2048] bf16: sin dump (pre-g)
    float* __restrict__ msum) {              // [32][512][512] f32: sum_d theta
    extern __shared__ char smem[];
    unsigned short* sc_lds = (unsigned short*)smem;
    unsigned short* XT0 = (unsigned short*)(smem + 116480);
    unsigned short* XT1 = (unsigned short*)(smem + 133120);

    const int tid = threadIdx.x;
    const int w = tid >> 6, l = tid & 63;
    const int c = l & 15, q = l >> 4;
    const int h = (c >> 3) & 1, bl = (c >> 2) & 1, d = c & 3, bd = c & 7;
    const int bglob = (int)blockIdx.x;       // one batch per block
    const int roff = q * 4 + 2 * h + bl;     // lane's row offset within tile
    const int ieoff = q * 4 + 2 * h;         // even row of the lane's (bl) pair

    // ---- XT0 init: sin rows (0-7) = 0, cos rows (8-15) = 1.0bf16 ----
    for (int idx = tid; idx < 16 * 260; idx += 512)
        ((unsigned*)XT0)[idx] = (idx < 8 * 260) ? 0u : 0x3f803f80u;
    // ---- stage LDS sc tiles 16..22 (global rows 256..367) ----
    {
        const unsigned* g32 = (const unsigned*)scb;
        unsigned* l32 = (unsigned*)sc_lds;
        for (int it = 0; it < 56; ++it) {
            int idx = it * 512 + tid;
            int row = idx >> 8, col = idx & 255;
            l32[row * 260 + col] = g32[(256 + row) * 256 + col];
        }
    }
    // ---- register tiles: rows [w*16,+16) and [128+w*16,+16) ----
    short8_t areg[32];
    {
        const unsigned short* a0 = scb + (size_t)(w * 16 + c) * 512 + q * 8;
        const unsigned short* a1 = scb + (size_t)(128 + w * 16 + c) * 512 + q * 8;
#pragma unroll
        for (int kk = 0; kk < 16; ++kk) {
            areg[kk] = *(const short8_t*)(a0 + kk * 32);
            areg[16 + kk] = *(const short8_t*)(a1 + kk * 32);
        }
    }
    const unsigned short* al2 = sc_lds + (w * 16 + c) * 520 + q * 8;               // w<7
    const unsigned short* gs2 = scb + (size_t)(256 + w * 16 + c) * 512 + q * 8;    // w==7
    const unsigned short* gs3 = scb + (size_t)(384 + w * 16 + c) * 512 + q * 8;

    float om[4], th[4], sn[4], cs[4];
#pragma unroll
    for (int mi = 0; mi < 4; ++mi) {
        int i = mi * 128 + w * 16 + roff;
        om[mi] = omega[i * 4 + d];
        th[mi] = 0.f; sn[mi] = 0.f; cs[mi] = 1.f;
    }
    __syncthreads();

    for (int t = 0; t < T_; ++t) {
        const unsigned short* bt = ((t & 1) ? XT1 : XT0) + c * 520 + q * 8;
        unsigned short* xw = (t & 1) ? XT0 : XT1;

        // gamma loads (1 per tile per lane; d-quad lanes broadcast-share)
        float gv[4];
        {
            const float* grow = gamma + ((size_t)bglob * 512 + t) * 512;
#pragma unroll
            for (int mi = 0; mi < 4; ++mi)
                gv[mi] = grow[mi * 128 + w * 16 + roff];
        }
        // batch-issue the streamed tile's 16 loads (one L2 round-trip)
        uint4 sreg[16];
#pragma unroll
        for (int kk = 0; kk < 16; ++kk)
            sreg[kk] = *(const uint4*)(gs3 + kk * 32);

        // MFMA coupling: 4 independent 16-deep chains
        float4_t ac0 = {0.f, 0.f, 0.f, 0.f}, ac1 = {0.f, 0.f, 0.f, 0.f};
        float4_t ac2 = {0.f, 0.f, 0.f, 0.f}, ac3 = {0.f, 0.f, 0.f, 0.f};
        if (w < 7) {
#pragma unroll
            for (int kk = 0; kk < 16; ++kk) {
                short8_t bf = *(const short8_t*)(bt + kk * 32);
                short8_t a2 = *(const short8_t*)(al2 + kk * 32);
                ac0 = __builtin_amdgcn_mfma_f32_16x16x32_bf16(areg[kk], bf, ac0, 0, 0, 0);
                ac1 = __builtin_amdgcn_mfma_f32_16x16x32_bf16(areg[16 + kk], bf, ac1, 0, 0, 0);
                ac2 = __builtin_amdgcn_mfma_f32_16x16x32_bf16(a2, bf, ac2, 0, 0, 0);
                ac3 = __builtin_amdgcn_mfma_f32_16x16x32_bf16(
                    __builtin_bit_cast(short8_t, sreg[kk]), bf, ac3, 0, 0, 0);
            }
        } else {
#pragma unroll
            for (int kk = 0; kk < 16; ++kk) {
                short8_t bf = *(const short8_t*)(bt + kk * 32);
                short8_t a2 = *(const short8_t*)(gs2 + kk * 32);
                ac0 = __builtin_amdgcn_mfma_f32_16x16x32_bf16(areg[kk], bf, ac0, 0, 0, 0);
                ac1 = __builtin_amdgcn_mfma_f32_16x16x32_bf16(areg[16 + kk], bf, ac1, 0, 0, 0);
                ac2 = __builtin_amdgcn_mfma_f32_16x16x32_bf16(a2, bf, ac2, 0, 0, 0);
                ac3 = __builtin_amdgcn_mfma_f32_16x16x32_bf16(
                    __builtin_bit_cast(short8_t, sreg[kk]), bf, ac3, 0, 0, 0);
            }
        }

        // combine st/ct halves (shfl 8), theta update, hw sincos (1 row per tile per lane)
#pragma unroll
        for (int mi = 0; mi < 4; ++mi) {
            float4_t acc = mi == 0 ? ac0 : mi == 1 ? ac1 : mi == 2 ? ac2 : ac3;
            float oA = bl ? acc[1] : acc[0];
            float oB = bl ? acc[3] : acc[2];
            float own = h ? oB : oA;
            float send = h ? oA : oB;
            float recv = __shfl_xor(send, 8, 64);
            float Sst = h ? recv : own;
            float Sct = h ? own : recv;
            float coup = cs[mi] * Sst - sn[mi] * Sct;
            th[mi] += 0.1f * (om[mi] + gv[mi] + (1.f / 512.f) * coup);
            sn[mi] = sin_hw(th[mi]);
            cs[mi] = cos_hw(th[mi]);
        }

        // write new st/ct into XT[next]: pack row-pair via shfl_xor(4); rows bd and 8+bd
        // (cols bd and 4+bd carry duplicated d=bd&3 vectors; both written, both full)
#pragma unroll
        for (int mi = 0; mi < 4; ++mi) {
            float psn = __shfl_xor(sn[mi], 4, 64);
            float pcs = __shfl_xor(cs[mi], 4, 64);
            float se = bl ? psn : sn[mi], so = bl ? sn[mi] : psn;
            float ce = bl ? pcs : cs[mi], co = bl ? cs[mi] : pcs;
            unsigned sp = f2bf(se) | (f2bf(so) << 16);
            unsigned cp = f2bf(ce) | (f2bf(co) << 16);
            int ib = mi * 128 + w * 16 + ieoff;
            ((unsigned*)xw)[(bd * 520 + ib) >> 1] = sp;
            ((unsigned*)xw)[((8 + bd) * 520 + ib) >> 1] = cp;
        }
        asm volatile("s_waitcnt lgkmcnt(0)" ::: "memory");
        __builtin_amdgcn_s_barrier();

        // ---- tail AFTER the barrier (registers + global only) ----
        // msum = sum over d (quad reduce); lane (l&3) stores tile (l&3)'s value
        {
            float m0 = th[0], m1 = th[1], m2 = th[2], m3 = th[3];
            m0 += __shfl_xor(m0, 1, 64); m0 += __shfl_xor(m0, 2, 64);
            m1 += __shfl_xor(m1, 1, 64); m1 += __shfl_xor(m1, 2, 64);
            m2 += __shfl_xor(m2, 1, 64); m2 += __shfl_xor(m2, 2, 64);
            m3 += __shfl_xor(m3, 1, 64); m3 += __shfl_xor(m3, 2, 64);
            float ms = (l & 2) ? ((l & 1) ? m3 : m2) : ((l & 1) ? m1 : m0);
            int i_own = (l & 3) * 128 + w * 16 + roff;
            msum[((size_t)bglob * 512 + t) * 512 + i_own] = ms;
        }
        // 4x4 lane transpose of sins (quad = d bits) -> natural feat layout, 8B store
        {
            float A0 = sn[0], A1 = sn[1], A2 = sn[2], A3 = sn[3];
            bool bit0 = (l & 1), bit1 = (l & 2);
            float sA = __shfl_xor(bit0 ? A0 : A1, 1, 64);
            float sB = __shfl_xor(bit0 ? A2 : A3, 1, 64);
            float B0 = bit0 ? sA : A0;
            float B1 = bit0 ? A1 : sA;
            float B2 = bit0 ? sB : A2;
            float B3 = bit0 ? A3 : sB;
            float sC = __shfl_xor(bit1 ? B0 : B2, 2, 64);
            float sD = __shfl_xor(bit1 ? B1 : B3, 2, 64);
            float c0 = bit1 ? sC : B0;
            float c1 = bit1 ? sD : B1;
            float c2 = bit1 ? B2 : sC;
            float c3 = bit1 ? B3 : sD;
            uint2 pk;
            pk.x = f2bf(c0) | (f2bf(c1) << 16);
            pk.y = f2bf(c2) | (f2bf(c3) << 16);
            int i_own = (l & 3) * 128 + w * 16 + roff;
            *(uint2*)(featb + ((size_t)bglob * 512 + t) * 2048 + i_own * 4) = pk;
        }
    }
}

// ---------------- post: g from msum, featb *= g (in place), gb = bf16(g_t) ----------------
__global__ __launch_bounds__(256) void post_kernel(
    const float* __restrict__ msum,      // [32][512][512]
    unsigned short* __restrict__ featb,  // [32][512][2048] RMW
    unsigned short* __restrict__ gb) {   // [32][512][512]
    int idx = blockIdx.x * 256 + threadIdx.x;  // 8,388,608
    int i = idx & 511;
    int t = (idx >> 9) & 511;
    int b = idx >> 18;
    int t2 = t < 2 ? 0 : t - 2;
    float m2 = msum[((size_t)b * 512 + t2) * 512 + i];
    float g = 0.5f + 0.5f * sin_hw(m2 * 0.25f);
    uint2* fp = (uint2*)(featb + ((size_t)b * 512 + t) * 2048 + i * 4);
    uint2 v = *fp;
    float f0 = bf2f(v.x & 0xffffu) * g;
    float f1 = __uint_as_float(v.x & 0xffff0000u) * g;
    float f2 = bf2f(v.y & 0xffffu) * g;
    float f3 = __uint_as_float(v.y & 0xffff0000u) * g;
    v.x = f2bf(f0) | (f2bf(f1) << 16);
    v.y = f2bf(f2) | (f2bf(f3) << 16);
    *fp = v;
    float mt = msum[((size_t)b * 512 + t) * 512 + i];
    gb[((size_t)b * 512 + t) * 512 + i] =
        (unsigned short)f2bf(0.5f + 0.5f * sin_hw(mt * 0.25f));
}

// ---------------- LIF membrane scan: cur(f32) -> spike f32 (in place) + bf16 copy ----------------
__global__ __launch_bounds__(256) void mem_scan_kernel(
    float* __restrict__ io, unsigned short* __restrict__ spb) {
    int tid = blockIdx.x * 256 + threadIdx.x;  // 65536 = B*H
    int h = tid & (H_ - 1), b = tid >> 11;
    float mem = 0.f;
    float* base = io + (size_t)b * T_ * H_ + h;
    unsigned short* sb = spb + (size_t)b * T_ * H_ + h;
    for (int t = 0; t < T_; ++t) {
        float cur = base[(size_t)t * H_];
        mem = 0.5f * mem + cur;
        float sp = 1.f / (1.f + __expf(-4.f * (mem - 1.f)));
        mem -= sp;
        base[(size_t)t * H_] = sp;
        sb[(size_t)t * H_] = (unsigned short)f2bf(sp);
    }
}

// ---------------- conv1d(k=5,pad=2) over T + log_softmax over C ----------------
__global__ __launch_bounds__(128) void conv_lsm_kernel(
    const float* __restrict__ snn, const float* __restrict__ Wc,
    const float* __restrict__ bc, float* __restrict__ out0) {
    __shared__ float sl[36 * 128];
    const int b = blockIdx.x >> 4;
    const int tt0 = (blockIdx.x & 15) * 32;
    const int co = threadIdx.x;
    for (int r = 0; r < 36; ++r) {
        int t = tt0 + r - 2;
        sl[r * 128 + co] = (t >= 0 && t < T_) ? snn[(size_t)(b * T_ + t) * 128 + co] : 0.f;
    }
    __syncthreads();
    float acc[32];
#pragma unroll
    for (int i = 0; i < 32; ++i) acc[i] = 0.f;
    for (int ci = 0; ci < 128; ++ci) {
        const float* wp = &Wc[(size_t)(co * 128 + ci) * 5];
        float w0 = wp[0], w1 = wp[1], w2 = wp[2], w3 = wp[3], w4 = wp[4];
        const float* col = &sl[ci];
        float r0 = col[0 * 128], r1 = col[1 * 128], r2 = col[2 * 128], r3 = col[3 * 128];
#pragma unroll
        for (int i = 0; i < 32; ++i) {
            float r4 = col[(i + 4) * 128];
            acc[i] += w0 * r0 + w1 * r1 + w2 * r2 + w3 * r3 + w4 * r4;
            r0 = r1; r1 = r2; r2 = r3; r3 = r4;
        }
    }
    float bco = bc[co];
    __syncthreads();
    float* cl = sl;
#pragma unroll
    for (int i = 0; i < 32; ++i) cl[i * 129 + co] = acc[i] + bco;
    __syncthreads();
    if (co < 32) {
        int t = tt0 + co;
        float mx = -3.4e38f;
        for (int cc = 0; cc < 128; ++cc) mx = fmaxf(mx, cl[co * 129 + cc]);
        float se = 0.f;
        for (int cc = 0; cc < 128; ++cc) se += __expf(cl[co * 129 + cc] - mx);
        float lse = mx + __logf(se);
        for (int cc = 0; cc < 128; ++cc)
            out0[((size_t)(b * 128 + cc)) * T_ + t] = cl[co * 129 + cc] - lse;
    }
}

// ---------------- launch ----------------
extern "C" void kernel_launch(void* const* d_in, const int* in_sizes, int n_in,
                              void* d_out, int out_size, void* d_ws, size_t ws_size,
                              hipStream_t stream) {
    (void)in_sizes; (void)n_in; (void)out_size; (void)ws_size;
    const float* x      = (const float*)d_in[0];
    const float* sc     = (const float*)d_in[1];
    const float* W_proj = (const float*)d_in[2];
    const float* b_proj = (const float*)d_in[3];
    const float* ln_g   = (const float*)d_in[4];
    const float* ln_b   = (const float*)d_in[5];
    const float* W_enc  = (const float*)d_in[6];
    const float* b_enc  = (const float*)d_in[7];
    const float* omega  = (const float*)d_in[8];
    const float* W_mask = (const float*)d_in[9];
    const float* b_mask = (const float*)d_in[10];
    const float* W_in   = (const float*)d_in[11];
    const float* b_in   = (const float*)d_in[12];
    const float* W_out  = (const float*)d_in[13];
    const float* b_out  = (const float*)d_in[14];
    const float* W_conv = (const float*)d_in[15];
    const float* b_conv = (const float*)d_in[16];

    float* out0 = (float*)d_out;                   // [B,C,T]
    float* out1 = out0 + (size_t)B_ * C_ * T_;     // [B,T,H] f32: cur -> spikes

    const int M = B_ * T_;  // 16384
    char* w = (char*)d_ws;
    float*          gamma  = (float*)w;                         // @0          33,554,432
    unsigned short* featb  = (unsigned short*)(w + 33554432);   // @33.5M      67,108,864
    float*          msum   = (float*)(w + 100663296);           // @100.7M     33,554,432
    unsigned short* gb     = (unsigned short*)(w + 134217728);  // @134.2M     16,777,216
    unsigned short* scb    = (unsigned short*)(w + 150994944);  // @151.0M        524,288
    unsigned short* wprojT = (unsigned short*)(w + 151519232);  // [2048,512]   2,097,152
    unsigned short* wencT  = (unsigned short*)(w + 153616384);  // [512,2048]   2,097,152
    unsigned short* winT   = (unsigned short*)(w + 155713536);  // [2048,2048]  8,388,608
    unsigned short* woutT  = (unsigned short*)(w + 164102144);  // [128,2048]     524,288
    unsigned short* wmT    = (unsigned short*)(w + 164626432);  // [512,512]      524,288
    unsigned short* xb  = gb;      // alias: xb dead before post writes gb
    unsigned short* Zb  = featb;   // alias: Z dead before scan writes featb
    unsigned short* spb = featb;   // alias: featb dead after G3
    float* snn_pre = gamma;        // alias: gamma dead after scan

    // conversions
    cvt_bf16_kernel<<<512, 256, 0, stream>>>(sc, (unsigned*)scb, 131072);
    cvt_bf16_kernel<<<16384, 256, 0, stream>>>(x, (unsigned*)xb, 4194304);
    cvt_T_kernel<<<dim3(64, 16), 256, 0, stream>>>(W_proj, wprojT, 512, 2048);
    cvt_T_kernel<<<dim3(16, 64), 256, 0, stream>>>(W_enc, wencT, 2048, 512);
    cvt_T_kernel<<<dim3(64, 64), 256, 0, stream>>>(W_in, winT, 2048, 2048);
    cvt_T_kernel<<<dim3(4, 64), 256, 0, stream>>>(W_out, woutT, 2048, 128);
    cvt_T_kernel<<<dim3(16, 16), 256, 0, stream>>>(W_mask, wmT, 512, 512);

    // G1: Zb = bf16(x @ W_proj + b_proj)
    gemm_bf16<1, false><<<dim3(16, 128), 256, 0, stream>>>(xb, wprojT, b_proj, Zb, M, H_, N_);
    // LN + LeakyReLU in place (bf16)
    ln_leaky_kernel<<<M, 256, 0, stream>>>(Zb, ln_g, ln_b);
    // G2: gamma(f32) = Zb @ W_enc + b_enc
    gemm_bf16<0, false><<<dim3(4, 128), 256, 0, stream>>>(Zb, wencT, b_enc, gamma, M, N_, H_);
    // theta scan -> featb (sin dump), msum   [32 blocks: one batch per block]
    scan_kernel<<<32, 512, SCAN_LDS_BYTES, stream>>>(scb, gamma, omega, featb, msum);
    // post: featb *= g_{t-2}, gb = bf16(g(theta_t))
    post_kernel<<<32768, 256, 0, stream>>>(msum, featb, gb);
    // deferred mask: featb *= sigmoid(gb_shift @ W_mask + b_mask)
    gemm_bf16<2, true><<<dim3(4, 128), 256, 0, stream>>>(gb, wmT, b_mask, featb, M, N_, N_);
    // G3: cur(f32, out1) = featb @ W_in + b_in
    gemm_bf16<0, false><<<dim3(16, 128), 256, 0, stream>>>(featb, winT, b_in, out1, M, H_, N_ * D_);
    // LIF membrane scan in place + bf16 spikes
    mem_scan_kernel<<<256, 256, 0, stream>>>(out1, spb);
    // G4: snn_pre(f32) = spikes @ W_out + b_out
    gemm_bf16<0, false><<<dim3(1, 128), 256, 0, stream>>>(spb, woutT, b_out, snn_pre, M, C_, H_);
    // conv1d + log_softmax -> out0
    conv_lsm_kernel<<<dim3(B_ * 16), 128, 0, stream>>>(snn_pre, W_conv, b_conv, out0);
}